// Round 11
// baseline (1547.919 us; speedup 1.0000x reference)
//
#include <hip/hip_runtime.h>
#include <hip/hip_bf16.h>
#include <math.h>

typedef __attribute__((ext_vector_type(8))) __bf16 bf8_t;
typedef __attribute__((ext_vector_type(4))) float f4_t;
typedef __attribute__((ext_vector_type(4))) int   i4_t;

#define XTOK 32768
#define NTOK 40960
#define DIMC 512

__device__ __forceinline__ void gload_lds16(const __bf16* g, __bf16* l) {
  __builtin_amdgcn_global_load_lds((const __attribute__((address_space(1))) void*)g,
                                   (__attribute__((address_space(3))) void*)l, 16, 0, 0);
}
__device__ __forceinline__ float bflo(unsigned u) { union { unsigned x; float f; } c; c.x = u << 16; return c.f; }
__device__ __forceinline__ float bfhi(unsigned u) { union { unsigned x; float f; } c; c.x = u & 0xffff0000u; return c.f; }

// ---------------- weight transpose + cast (LDS-tiled): WT[n][k] = W[k][n] ----------------
__global__ void transpose_cast(const float* __restrict__ W, __bf16* __restrict__ WT,
                               int K, int N) {
  __shared__ float t[32][33];
  int bn = blockIdx.x * 32, bk = blockIdx.y * 32;
  int tx = threadIdx.x & 31, ty = threadIdx.x >> 5;   // 32 x 8
#pragma unroll
  for (int i = 0; i < 4; ++i)
    t[ty + i * 8][tx] = W[(size_t)(bk + ty + i * 8) * N + bn + tx];
  __syncthreads();
#pragma unroll
  for (int i = 0; i < 4; ++i)
    WT[(size_t)(bn + ty + i * 8) * K + bk + tx] = (__bf16)t[tx][ty + i * 8];
}

// ---------------- token pack: window-order gather + resize, fp32 -> bf16 ----------------
__global__ void pack_tokens(const float* __restrict__ x, const float* __restrict__ y,
                            __bf16* __restrict__ Asrc, __bf16* __restrict__ Aoth,
                            int* __restrict__ srcoff, int* __restrict__ outoff) {
  int g = blockIdx.x;           // window-ordered token row, 0..40959
  int t = threadIdx.x;          // 256 threads, 2 channels each
  int b, h, w; int soff, ooff; bool isx = (g < XTOK);
  if (isx) {
    b = g >> 12;
    int w5 = g & 4095;
    int widx = w5 >> 8, tt = w5 & 255;
    int wh = widx >> 2, ww = widx & 3;
    h = wh * 16 + (tt >> 4); w = ww * 16 + (tt & 15);
    int n = h * 64 + w;
    soff = (b * 4096 + n) * 512;
    ooff = (b * 5120 + n) * 512;
  } else {
    int gy = g - XTOK;
    b = gy >> 10;
    int w5 = gy & 1023;
    int widx = w5 >> 8, tt = w5 & 255;
    int wh = widx >> 1, ww = widx & 1;
    h = wh * 16 + (tt >> 4); w = ww * 16 + (tt & 15);
    int n = h * 32 + w;
    soff = (b * 1024 + n) * 512;
    ooff = (b * 5120 + 4096 + n) * 512;
  }
  if (t == 0) { srcoff[g] = soff; outoff[g] = ooff; }
  const float* sp = (isx ? x : y) + (size_t)soff + t * 2;
  float2 sv = *(const float2*)sp;
  size_t gb = (size_t)g * 512 + t * 2;
  Asrc[gb]     = (__bf16)sv.x;
  Asrc[gb + 1] = (__bf16)sv.y;

  float o0, o1;
  if (isx) {
    // bilinear upsample 32x32 -> 64x64, half-pixel centers, edge clamp
    int h0, h1, w0i, w1i; float fh0, fh1, fw0, fw1;
    if (h & 1) { h0 = h >> 1; h1 = (h0 + 1 < 31) ? h0 + 1 : 31; fh0 = 0.75f; fh1 = 0.25f; }
    else       { h1 = h >> 1; h0 = (h1 - 1 > 0) ? h1 - 1 : 0;   fh0 = 0.25f; fh1 = 0.75f; }
    if (w & 1) { w0i = w >> 1; w1i = (w0i + 1 < 31) ? w0i + 1 : 31; fw0 = 0.75f; fw1 = 0.25f; }
    else       { w1i = w >> 1; w0i = (w1i - 1 > 0) ? w1i - 1 : 0;   fw0 = 0.25f; fw1 = 0.75f; }
    const float* yb = y + (size_t)b * 1024 * 512 + t * 2;
    float2 v00 = *(const float2*)(yb + (h0 * 32 + w0i) * 512);
    float2 v01 = *(const float2*)(yb + (h0 * 32 + w1i) * 512);
    float2 v10 = *(const float2*)(yb + (h1 * 32 + w0i) * 512);
    float2 v11 = *(const float2*)(yb + (h1 * 32 + w1i) * 512);
    o0 = fh0 * (fw0 * v00.x + fw1 * v01.x) + fh1 * (fw0 * v10.x + fw1 * v11.x);
    o1 = fh0 * (fw0 * v00.y + fw1 * v01.y) + fh1 * (fw0 * v10.y + fw1 * v11.y);
  } else {
    // bilinear downsample 64x64 -> 32x32 == 2x2 average pool
    const float* xb = x + (size_t)b * 4096 * 512 + t * 2;
    float2 v00 = *(const float2*)(xb + ((2 * h) * 64 + 2 * w) * 512);
    float2 v01 = *(const float2*)(xb + ((2 * h) * 64 + 2 * w + 1) * 512);
    float2 v10 = *(const float2*)(xb + ((2 * h + 1) * 64 + 2 * w) * 512);
    float2 v11 = *(const float2*)(xb + ((2 * h + 1) * 64 + 2 * w + 1) * 512);
    o0 = 0.25f * (v00.x + v01.x + v10.x + v11.x);
    o1 = 0.25f * (v00.y + v01.y + v10.y + v11.y);
  }
  Aoth[gb]     = (__bf16)o0;
  Aoth[gb + 1] = (__bf16)o1;
}

// ---------------- GEMM v7: 128^2 tile, BK=64, A-only LDS (2 slots), B from L2, 4 blk/CU -----
// C[M,N] = A[M,K] @ BT[N,K]^T + bias.  256 thr (2x2 waves), 1-D grid, XCD m-major swizzle.
// B-tiles are <=2MB (L2-resident): bv fragments read straight from global, issued BEFORE the
// A-stage so the vmcnt FIFO lets staging loads stay outstanding. LDS 34KB -> 4 blocks/CU.
// EPI 0: out bf16 = acc + bias                     (K-proj)
// EPI 1: out bf16 = acc + bias + residual(src gather)              (Wo -> toksb)
// EPI 2: out bf16 = gelu_exact(acc + bias)         (MLP1)
// EPI 3: fp32 dout at permuted offset = acc + bias + (float)toksb  (MLP2)
// EPI 4: fused QV: n0<512 -> outb (Q, bias), else outb2 (V, bias2)
template<int EPI>
__global__ __launch_bounds__(256, 4)
void gemm_bt(const __bf16* __restrict__ A, const __bf16* __restrict__ BT,
             const float* __restrict__ bias, const float* __restrict__ bias2,
             int K, int nbn, int row0,
             __bf16* __restrict__ outb, __bf16* __restrict__ outb2,
             const float* __restrict__ resx, const float* __restrict__ resy,
             const int* __restrict__ srcoff, const int* __restrict__ outoff,
             const __bf16* __restrict__ toksr, float* __restrict__ dout) {
  const int N = nbn * 128;
  __shared__ __align__(16) __bf16 smem[17408];     // 34816 B: A slots = first 32768 B
  // bijective XCD swizzle (m204): contiguous m-major chunk per XCD
  int nwg = gridDim.x;
  int qq = nwg >> 3, rr = nwg & 7;
  int xcd = blockIdx.x & 7, base = blockIdx.x >> 3;
  int wg = (xcd < rr ? xcd * (qq + 1) : rr * (qq + 1) + (xcd - rr) * qq) + base;
  int bm = wg / nbn, bn = wg - bm * nbn;
  int m0 = bm * 128, n0 = bn * 128;

  int tid = threadIdx.x, lane = tid & 63, wid = tid >> 6;
  int wr = wid >> 1, wc = wid & 1;
  int ln15 = lane & 15, kq = lane >> 4;

  f4_t acc[4][4];
#pragma unroll
  for (int m = 0; m < 4; ++m)
#pragma unroll
    for (int n = 0; n < 4; ++n) acc[m][n] = f4_t{0.f, 0.f, 0.f, 0.f};

  // stage A-tile 128x64 into slot (16KB), 4 gload_lds16/thread; src chunk pre-swizzled.
  auto stage = [&](int slot, int k0) {
#pragma unroll
    for (int i = 0; i < 4; ++i) {
      int ci = wid * 256 + i * 64 + lane;          // 1024 chunks of 16B
      int row = ci >> 3;
      int gc = (ci & 7) ^ (row & 7);
      gload_lds16(A + (size_t)(m0 + row) * K + k0 + gc * 8,
                  &smem[slot * 8192 + (wid * 4 + i) * 512]);
    }
  };

  // per-thread B row bases (16 B/lane fragments, L2-resident)
  const __bf16* bptr0[4];
#pragma unroll
  for (int n = 0; n < 4; ++n)
    bptr0[n] = BT + (size_t)(n0 + wc * 64 + n * 16 + ln15) * K + kq * 8;

  int nt = K >> 6;
  stage(0, 0);
  __syncthreads();
  for (int t = 0; t < nt; ++t) {
    int s = t & 1;
    int k0 = t << 6;
    // B fragments from global FIRST (older in vmcnt FIFO than the stage below)
    bf8_t bv[4][2];
#pragma unroll
    for (int n = 0; n < 4; ++n)
#pragma unroll
      for (int k2 = 0; k2 < 2; ++k2)
        bv[n][k2] = *(const bf8_t*)(bptr0[n] + k0 + k2 * 32);
    if (t + 1 < nt) stage(s ^ 1, (t + 1) << 6);
    const __bf16* At = &smem[s * 8192];
    bf8_t av[4][2];
#pragma unroll
    for (int m = 0; m < 4; ++m) {
      int row = wr * 64 + m * 16 + ln15;
#pragma unroll
      for (int k2 = 0; k2 < 2; ++k2)
        av[m][k2] = *(const bf8_t*)&At[row * 64 + (((k2 * 4 + kq) ^ (row & 7)) << 3)];
    }
    __builtin_amdgcn_s_setprio(1);
#pragma unroll
    for (int k2 = 0; k2 < 2; ++k2)
#pragma unroll
      for (int m = 0; m < 4; ++m)
#pragma unroll
        for (int n = 0; n < 4; ++n)
          acc[m][n] = __builtin_amdgcn_mfma_f32_16x16x32_bf16(av[m][k2], bv[n][k2], acc[m][n], 0, 0, 0);
    __builtin_amdgcn_s_setprio(0);
    __syncthreads();   // next tile's stage (issued one full iteration ago) drains here
  }

  bool hi = (EPI == 4) && (n0 >= 512);
  const float* bp = hi ? bias2 : bias;
  int nbase = hi ? n0 - 512 : n0;
  float bs[4];
#pragma unroll
  for (int n = 0; n < 4; ++n) bs[n] = bp[nbase + wc * 64 + n * 16 + ln15];

  // ---- transform acc in place ----
#pragma unroll
  for (int m = 0; m < 4; ++m) {
    int lr2 = m0 + wr * 64 + m * 16 + kq * 4;
#pragma unroll
    for (int r = 0; r < 4; ++r) {
      int grow = row0 + lr2 + r;
      const float* rptr = nullptr; int so = 0;
      if (EPI == 1) { so = srcoff[grow]; rptr = (grow < XTOK) ? resx : resy; }
#pragma unroll
      for (int n = 0; n < 4; ++n) {
        int gcol = nbase + wc * 64 + n * 16 + ln15;
        float v = acc[m][n][r] + bs[n];
        if (EPI == 1) v += rptr[(size_t)so + gcol];
        if (EPI == 2) v = 0.5f * v * (1.0f + erff(v * 0.7071067811865475f));
        if (EPI == 3) v += (float)toksr[(size_t)grow * DIMC + gcol];
        acc[m][n][r] = v;
      }
    }
  }

  if (EPI != 3) {
    // bf16 full-tile stage [128][136] -> 256B-contiguous row writes
#pragma unroll
    for (int m = 0; m < 4; ++m)
#pragma unroll
      for (int r = 0; r < 4; ++r)
#pragma unroll
        for (int n = 0; n < 4; ++n)
          smem[(wr * 64 + m * 16 + kq * 4 + r) * 136 + wc * 64 + n * 16 + ln15] = (__bf16)acc[m][n][r];
    __syncthreads();
    __bf16* ob = (EPI == 4 && hi) ? outb2 : outb;
    int ldn = (EPI == 2) ? N : 512;
    int gc0 = (EPI == 2) ? n0 : nbase;
#pragma unroll
    for (int it = 0; it < 8; ++it) {
      int cid = it * 256 + tid;                    // 2048 chunks = 128 rows x 16
      int row = cid >> 4, c = cid & 15;
      i4_t v = *(const i4_t*)&smem[row * 136 + c * 8];
      *(i4_t*)&ob[(size_t)(m0 + row) * ldn + gc0 + c * 8] = v;
    }
  } else {
    // fp32 stage in two 64-col halves [128][68] -> permuted-row d_out writes
    float* stf = (float*)smem;
#pragma unroll
    for (int h = 0; h < 2; ++h) {
      __syncthreads();
      if (wc == h) {
#pragma unroll
        for (int m = 0; m < 4; ++m)
#pragma unroll
          for (int r = 0; r < 4; ++r)
#pragma unroll
            for (int n = 0; n < 4; ++n)
              stf[(wr * 64 + m * 16 + kq * 4 + r) * 68 + n * 16 + ln15] = acc[m][n][r];
      }
      __syncthreads();
#pragma unroll
      for (int it = 0; it < 8; ++it) {
        int cid = it * 256 + tid;                  // 2048 f4 chunks = 128 rows x 16
        int row = cid >> 4, c = cid & 15;
        f4_t v = *(const f4_t*)&stf[row * 68 + c * 4];
        int oo = outoff[row0 + m0 + row];
        *(f4_t*)&dout[(size_t)oo + n0 + h * 64 + c * 4] = v;
      }
    }
  }
}

// ---------------- windowed attention v5: swapped-QK, packed-S, no spill ----------------
__global__ __launch_bounds__(512, 4)
void attn_kernel(const __bf16* __restrict__ Qb, const __bf16* __restrict__ Kb,
                 const __bf16* __restrict__ Vb, __bf16* __restrict__ AOb) {
  __shared__ __align__(16) __bf16 smem[32768];       // Kl[16384] + Vt[16384]
  __bf16* Kl = smem;                                  // chunk16 i = s*8 + (c ^ (s&7))
  __bf16* Vt = smem + 16384;                          // el(d,s) = d*256 + (((s>>3)^(d>>3)^(d&7))<<3) + (s&7)
  int tid = threadIdx.x, lane = tid & 63, wid = tid >> 6;
  int l15 = lane & 15, kq = lane >> 4;
  int win = blockIdx.x >> 3, head = blockIdx.x & 7;
  size_t wtok = (size_t)win * 256;
  int hc = head * 64;

#pragma unroll
  for (int it = 0; it < 4; ++it) {
    int i = (wid * 4 + it) * 64 + lane;
    int s = i >> 3, cp = i & 7, c = cp ^ (s & 7);
    gload_lds16(Kb + (wtok + s) * 512 + hc + c * 8, &Kl[(size_t)((wid * 4 + it) * 64) * 8]);
  }
#pragma unroll
  for (int it = 0; it < 4; ++it) {
    int j = tid + it * 512;
    int dc = j & 7, s = j >> 3;
    i4_t v = *(const i4_t*)(Vb + (wtok + s) * 512 + hc + dc * 8);
    const __bf16* ve = (const __bf16*)&v;
#pragma unroll
    for (int jj = 0; jj < 8; ++jj) {
      int d = dc * 8 + jj;
      int sc = (s >> 3) ^ (((d >> 3) ^ d) & 7);
      Vt[d * 256 + (sc << 3) + (s & 7)] = ve[jj];
    }
  }
  __syncthreads();

  const float CLOG2E = 0.18033688011112043f;        // 0.125 * log2(e)
  f4_t oacc[2][4];
  float rinvq[2];
  int sl0 = ((kq & 1) << 5) + l15;
  int sl1 = sl0 + 16;
  bool hiT = (kq & 2) != 0;

#pragma unroll
  for (int qt = 0; qt < 2; ++qt) {
    int qbase = wid * 32 + qt * 16;
    bf8_t qf[2];
#pragma unroll
    for (int k2 = 0; k2 < 2; ++k2)
      qf[k2] = *(const bf8_t*)(Qb + (wtok + qbase + l15) * 512 + hc + k2 * 32 + kq * 8);

    uint2 ps[16];
    float mx = -3.0e38f;
    __builtin_amdgcn_s_setprio(1);
#pragma unroll
    for (int st = 0; st < 16; ++st) {
      f4_t z = {0.f, 0.f, 0.f, 0.f};
      int s = st * 16 + l15;
#pragma unroll
      for (int k2 = 0; k2 < 2; ++k2) {
        int c = (k2 * 4 + kq) ^ (s & 7);
        bf8_t kf = *(const bf8_t*)&Kl[(s * 8 + c) * 8];
        z = __builtin_amdgcn_mfma_f32_16x16x32_bf16(kf, qf[k2], z, 0, 0, 0);
      }
      z *= CLOG2E;
      mx = fmaxf(mx, fmaxf(fmaxf(z[0], z[1]), fmaxf(z[2], z[3])));
      union { __bf16 b[4]; uint2 u; } pk;
#pragma unroll
      for (int r = 0; r < 4; ++r) pk.b[r] = (__bf16)z[r];
      ps[st] = pk.u;
    }
    __builtin_amdgcn_s_setprio(0);
    mx = fmaxf(mx, __shfl_xor(mx, 16, 64));
    mx = fmaxf(mx, __shfl_xor(mx, 32, 64));

    float L = 0.f;
#pragma unroll
    for (int st = 0; st < 16; ++st) {
      uint2 u = ps[st];
      float p0 = __builtin_amdgcn_exp2f(bflo(u.x) - mx);
      float p1 = __builtin_amdgcn_exp2f(bfhi(u.x) - mx);
      float p2 = __builtin_amdgcn_exp2f(bflo(u.y) - mx);
      float p3 = __builtin_amdgcn_exp2f(bfhi(u.y) - mx);
      L += (p0 + p1) + (p2 + p3);
      union { __bf16 b[4]; uint2 u; } pk;
      pk.b[0] = (__bf16)p0; pk.b[1] = (__bf16)p1; pk.b[2] = (__bf16)p2; pk.b[3] = (__bf16)p3;
      ps[st] = pk.u;
    }
    L += __shfl_xor(L, 16, 64);
    L += __shfl_xor(L, 32, 64);
    rinvq[qt] = 1.0f / L;

#pragma unroll
    for (int dn = 0; dn < 4; ++dn) oacc[qt][dn] = f4_t{0.f, 0.f, 0.f, 0.f};
    __builtin_amdgcn_s_setprio(1);
#pragma unroll
    for (int c = 0; c < 8; ++c) {
      uint2 t0 = ps[2 * c], t1 = ps[2 * c + 1];
      int a00x = __shfl((int)t0.x, sl0, 64), a00y = __shfl((int)t0.y, sl0, 64);
      int a01x = __shfl((int)t0.x, sl1, 64), a01y = __shfl((int)t0.y, sl1, 64);
      int a10x = __shfl((int)t1.x, sl0, 64), a10y = __shfl((int)t1.y, sl0, 64);
      int a11x = __shfl((int)t1.x, sl1, 64), a11y = __shfl((int)t1.y, sl1, 64);
      union { int u[4]; bf8_t v; } fr;
      fr.u[0] = hiT ? a10x : a00x;
      fr.u[1] = hiT ? a10y : a00y;
      fr.u[2] = hiT ? a11x : a01x;
      fr.u[3] = hiT ? a11y : a01y;
#pragma unroll
      for (int dn = 0; dn < 4; ++dn) {
        int d = dn * 16 + l15;
        int sc = (4 * c + kq) ^ (((d >> 3) ^ d) & 7);
        bf8_t vf = *(const bf8_t*)&Vt[d * 256 + (sc << 3)];
        oacc[qt][dn] = __builtin_amdgcn_mfma_f32_16x16x32_bf16(fr.v, vf, oacc[qt][dn], 0, 0, 0);
      }
    }
    __builtin_amdgcn_s_setprio(0);
  }

  __syncthreads();
  __bf16* Ko = smem + wid * 2304;                    // [32][72]
#pragma unroll
  for (int qt = 0; qt < 2; ++qt)
#pragma unroll
    for (int dn = 0; dn < 4; ++dn)
#pragma unroll
      for (int r = 0; r < 4; ++r)
        Ko[(qt * 16 + kq * 4 + r) * 72 + dn * 16 + l15] = (__bf16)(oacc[qt][dn][r] * rinvq[qt]);
#pragma unroll
  for (int it = 0; it < 4; ++it) {
    int lr = it * 8 + (lane >> 3), cb = (lane & 7) * 8;
    i4_t v = *(const i4_t*)&Ko[lr * 72 + cb];
    *(i4_t*)&AOb[(wtok + wid * 32 + lr) * 512 + hc + cb] = v;
  }
}

extern "C" void kernel_launch(void* const* d_in, const int* in_sizes, int n_in,
                              void* d_out, int out_size, void* d_ws, size_t ws_size,
                              hipStream_t stream) {
  const float* x  = (const float*)d_in[0];
  const float* y  = (const float*)d_in[1];
  const float* Wq = (const float*)d_in[2];
  const float* bq = (const float*)d_in[3];
  const float* Wk = (const float*)d_in[4];
  const float* bk = (const float*)d_in[5];
  const float* Wv = (const float*)d_in[6];
  const float* bv = (const float*)d_in[7];
  const float* Wo = (const float*)d_in[8];
  const float* bo = (const float*)d_in[9];
  const float* W1 = (const float*)d_in[10];
  const float* b1 = (const float*)d_in[11];
  const float* W2 = (const float*)d_in[12];
  const float* b2 = (const float*)d_in[13];

  char* ws = (char*)d_ws;
  size_t off = 0;
  auto carve = [&](size_t bytes) -> void* {
    void* p = ws + off;
    off += (bytes + 255) & ~(size_t)255;
    return p;
  };
  __bf16* WqvT = (__bf16*)carve((size_t)1024 * 512 * 2);  // [Wq^T; Wv^T]
  __bf16* WkT  = (__bf16*)carve((size_t)512 * 512 * 2);
  __bf16* WoT  = (__bf16*)carve((size_t)512 * 512 * 2);
  __bf16* W1T  = (__bf16*)carve((size_t)2048 * 512 * 2);
  __bf16* W2T  = (__bf16*)carve((size_t)512 * 2048 * 2);
  int* srcoff = (int*)carve((size_t)NTOK * 4);
  int* outoff = (int*)carve((size_t)NTOK * 4);
  __bf16* Asrc = (__bf16*)carve((size_t)NTOK * 512 * 2);
  __bf16* Aoth = (__bf16*)carve((size_t)NTOK * 512 * 2);
  __bf16* Qb   = (__bf16*)carve((size_t)NTOK * 512 * 2);
  __bf16* Kb   = (__bf16*)carve((size_t)NTOK * 512 * 2);
  __bf16* Vb   = (__bf16*)carve((size_t)NTOK * 512 * 2);
  // aliases (lifetimes: producer of alias runs after last reader of original)
  __bf16* AOb   = Asrc;              // attention out  (Asrc dead after QV-GEMM)
  __bf16* toksb = Aoth;              // tokens bf16    (Aoth dead after K-GEMM)
  __bf16* Hb    = Qb;                // MLP hidden chunk (Q/K/V dead after attention);
                                     // nc=2: 20480*2048*2B = 84MB <= Qb+Kb+Vb region (126MB)
  float*  dout  = (float*)d_out;

  dim3 tb(256);
  transpose_cast<<<dim3(512 / 32, 512 / 32), tb, 0, stream>>>(Wq, WqvT, 512, 512);
  transpose_cast<<<dim3(512 / 32, 512 / 32), tb, 0, stream>>>(Wv, WqvT + (size_t)512 * 512, 512, 512);
  transpose_cast<<<dim3(512 / 32, 512 / 32), tb, 0, stream>>>(Wk, WkT, 512, 512);
  transpose_cast<<<dim3(512 / 32, 512 / 32), tb, 0, stream>>>(Wo, WoT, 512, 512);
  transpose_cast<<<dim3(2048 / 32, 512 / 32), tb, 0, stream>>>(W1, W1T, 512, 2048);
  transpose_cast<<<dim3(512 / 32, 2048 / 32), tb, 0, stream>>>(W2, W2T, 2048, 512);

  pack_tokens<<<NTOK, 256, 0, stream>>>(x, y, Asrc, Aoth, srcoff, outoff);

  gemm_bt<4><<<NTOK / 128 * 8, 256, 0, stream>>>(Asrc, WqvT, bq, bv, 512, 8, 0, Qb, Vb, nullptr, nullptr, nullptr, nullptr, nullptr, nullptr);
  gemm_bt<0><<<NTOK / 128 * 4, 256, 0, stream>>>(Aoth, WkT, bk, nullptr, 512, 4, 0, Kb, nullptr, nullptr, nullptr, nullptr, nullptr, nullptr, nullptr);

  attn_kernel<<<160 * 8, 512, 0, stream>>>(Qb, Kb, Vb, AOb);

  gemm_bt<1><<<NTOK / 128 * 4, 256, 0, stream>>>(AOb, WoT, bo, nullptr, 512, 4, 0, toksb, nullptr, x, y, srcoff, nullptr, nullptr, nullptr);

  const int nc = 2, rows = NTOK / 2;                 // Hb (84MB) fits the dead Q/K/V region
  for (int c = 0; c < nc; ++c) {
    int r0 = c * rows;
    gemm_bt<2><<<rows / 128 * 16, 256, 0, stream>>>(toksb + (size_t)r0 * 512, W1T, b1, nullptr, 512, 16, r0, Hb, nullptr, nullptr, nullptr, nullptr, nullptr, nullptr, nullptr);
    gemm_bt<3><<<rows / 128 * 4, 256, 0, stream>>>(Hb, W2T, b2, nullptr, 2048, 4, r0, nullptr, nullptr, nullptr, nullptr, nullptr, outoff, toksb, dout);
  }
}

// Round 12
// 629.241 us; speedup vs baseline: 2.4600x; 2.4600x over previous
//
#include <hip/hip_runtime.h>
#include <hip/hip_bf16.h>
#include <math.h>

typedef __attribute__((ext_vector_type(8))) __bf16 bf8_t;
typedef __attribute__((ext_vector_type(4))) float f4_t;
typedef __attribute__((ext_vector_type(4))) int   i4_t;

#define XTOK 32768
#define NTOK 40960
#define DIMC 512

__device__ __forceinline__ void gload_lds16(const __bf16* g, __bf16* l) {
  __builtin_amdgcn_global_load_lds((const __attribute__((address_space(1))) void*)g,
                                   (__attribute__((address_space(3))) void*)l, 16, 0, 0);
}
__device__ __forceinline__ float bflo(unsigned u) { union { unsigned x; float f; } c; c.x = u << 16; return c.f; }
__device__ __forceinline__ float bfhi(unsigned u) { union { unsigned x; float f; } c; c.x = u & 0xffff0000u; return c.f; }

// ---------------- weight transpose + cast (LDS-tiled): WT[n][k] = W[k][n] ----------------
__global__ void transpose_cast(const float* __restrict__ W, __bf16* __restrict__ WT,
                               int K, int N) {
  __shared__ float t[32][33];
  int bn = blockIdx.x * 32, bk = blockIdx.y * 32;
  int tx = threadIdx.x & 31, ty = threadIdx.x >> 5;   // 32 x 8
#pragma unroll
  for (int i = 0; i < 4; ++i)
    t[ty + i * 8][tx] = W[(size_t)(bk + ty + i * 8) * N + bn + tx];
  __syncthreads();
#pragma unroll
  for (int i = 0; i < 4; ++i)
    WT[(size_t)(bn + ty + i * 8) * K + bk + tx] = (__bf16)t[tx][ty + i * 8];
}

// ---------------- token pack: window-order gather + resize, fp32 -> bf16 ----------------
__global__ void pack_tokens(const float* __restrict__ x, const float* __restrict__ y,
                            __bf16* __restrict__ Asrc, __bf16* __restrict__ Aoth,
                            int* __restrict__ srcoff, int* __restrict__ outoff) {
  int g = blockIdx.x;           // window-ordered token row, 0..40959
  int t = threadIdx.x;          // 256 threads, 2 channels each
  int b, h, w; int soff, ooff; bool isx = (g < XTOK);
  if (isx) {
    b = g >> 12;
    int w5 = g & 4095;
    int widx = w5 >> 8, tt = w5 & 255;
    int wh = widx >> 2, ww = widx & 3;
    h = wh * 16 + (tt >> 4); w = ww * 16 + (tt & 15);
    int n = h * 64 + w;
    soff = (b * 4096 + n) * 512;
    ooff = (b * 5120 + n) * 512;
  } else {
    int gy = g - XTOK;
    b = gy >> 10;
    int w5 = gy & 1023;
    int widx = w5 >> 8, tt = w5 & 255;
    int wh = widx >> 1, ww = widx & 1;
    h = wh * 16 + (tt >> 4); w = ww * 16 + (tt & 15);
    int n = h * 32 + w;
    soff = (b * 1024 + n) * 512;
    ooff = (b * 5120 + 4096 + n) * 512;
  }
  if (t == 0) { srcoff[g] = soff; outoff[g] = ooff; }
  const float* sp = (isx ? x : y) + (size_t)soff + t * 2;
  float2 sv = *(const float2*)sp;
  size_t gb = (size_t)g * 512 + t * 2;
  Asrc[gb]     = (__bf16)sv.x;
  Asrc[gb + 1] = (__bf16)sv.y;

  float o0, o1;
  if (isx) {
    // bilinear upsample 32x32 -> 64x64, half-pixel centers, edge clamp
    int h0, h1, w0i, w1i; float fh0, fh1, fw0, fw1;
    if (h & 1) { h0 = h >> 1; h1 = (h0 + 1 < 31) ? h0 + 1 : 31; fh0 = 0.75f; fh1 = 0.25f; }
    else       { h1 = h >> 1; h0 = (h1 - 1 > 0) ? h1 - 1 : 0;   fh0 = 0.25f; fh1 = 0.75f; }
    if (w & 1) { w0i = w >> 1; w1i = (w0i + 1 < 31) ? w0i + 1 : 31; fw0 = 0.75f; fw1 = 0.25f; }
    else       { w1i = w >> 1; w0i = (w1i - 1 > 0) ? w1i - 1 : 0;   fw0 = 0.25f; fw1 = 0.75f; }
    const float* yb = y + (size_t)b * 1024 * 512 + t * 2;
    float2 v00 = *(const float2*)(yb + (h0 * 32 + w0i) * 512);
    float2 v01 = *(const float2*)(yb + (h0 * 32 + w1i) * 512);
    float2 v10 = *(const float2*)(yb + (h1 * 32 + w0i) * 512);
    float2 v11 = *(const float2*)(yb + (h1 * 32 + w1i) * 512);
    o0 = fh0 * (fw0 * v00.x + fw1 * v01.x) + fh1 * (fw0 * v10.x + fw1 * v11.x);
    o1 = fh0 * (fw0 * v00.y + fw1 * v01.y) + fh1 * (fw0 * v10.y + fw1 * v11.y);
  } else {
    // bilinear downsample 64x64 -> 32x32 == 2x2 average pool
    const float* xb = x + (size_t)b * 4096 * 512 + t * 2;
    float2 v00 = *(const float2*)(xb + ((2 * h) * 64 + 2 * w) * 512);
    float2 v01 = *(const float2*)(xb + ((2 * h) * 64 + 2 * w + 1) * 512);
    float2 v10 = *(const float2*)(xb + ((2 * h + 1) * 64 + 2 * w) * 512);
    float2 v11 = *(const float2*)(xb + ((2 * h + 1) * 64 + 2 * w + 1) * 512);
    o0 = 0.25f * (v00.x + v01.x + v10.x + v11.x);
    o1 = 0.25f * (v00.y + v01.y + v10.y + v11.y);
  }
  Aoth[gb]     = (__bf16)o0;
  Aoth[gb + 1] = (__bf16)o1;
}

// ---------------- GEMM v8: 128^2 tile, BK=32, 2-slot dbuf (34.8KB LDS), 1 barrier/K-step ----
// C[M,N] = A[M,K] @ BT[N,K]^T + bias.  256 thr (2x2 waves), 1-D grid, XCD m-major swizzle.
// R6 schedule (stage t+1 before reads of t, single end barrier) at R5's LDS footprint:
// 2 slots x 16KB -> hardware can fit 4 blocks/CU (VGPR ~100, launch_bounds(256,2) cap 256).
// Staging/read swizzle identical to refcheck-passed R9: chunk ^= (row&3)^((row>>2)&3).
// EPI 0: out bf16 = acc + bias                     (K-proj)
// EPI 1: v = acc + bias + residual(src gather); write fp32 toks + bf16 toks   (Wo)
// EPI 2: out bf16 = gelu_exact(acc + bias)         (MLP1)
// EPI 3: v = acc + bias + toksf; write d_out at permuted offset (MLP2)
// EPI 4: fused QV: n0<512 -> outb (Q, bias), else outb2 (V, bias2)
template<int EPI>
__global__ __launch_bounds__(256, 2)
void gemm_bt(const __bf16* __restrict__ A, const __bf16* __restrict__ BT,
             const float* __restrict__ bias, const float* __restrict__ bias2,
             int K, int nbn, int row0,
             __bf16* __restrict__ outb, __bf16* __restrict__ outb2,
             float* __restrict__ outf,
             const float* __restrict__ resx, const float* __restrict__ resy,
             const int* __restrict__ srcoff, const int* __restrict__ outoff,
             const float* __restrict__ toksf, float* __restrict__ dout) {
  const int N = nbn * 128;
  __shared__ __align__(16) __bf16 smem[17408];     // 34816B: 2 slots x 8192 el; epilogue reuse
  // bijective XCD swizzle (m204): contiguous m-major chunk per XCD
  int nwg = gridDim.x;
  int qq = nwg >> 3, rr = nwg & 7;
  int xcd = blockIdx.x & 7, base = blockIdx.x >> 3;
  int wg = (xcd < rr ? xcd * (qq + 1) : rr * (qq + 1) + (xcd - rr) * qq) + base;
  int bm = wg / nbn, bn = wg - bm * nbn;
  int m0 = bm * 128, n0 = bn * 128;

  int tid = threadIdx.x, lane = tid & 63, wid = tid >> 6;
  int wr = wid >> 1, wc = wid & 1;
  int ln15 = lane & 15, kq = lane >> 4;

  f4_t acc[4][4];
#pragma unroll
  for (int m = 0; m < 4; ++m)
#pragma unroll
    for (int n = 0; n < 4; ++n) acc[m][n] = f4_t{0.f, 0.f, 0.f, 0.f};

  // stage K-tile kt into slot. 4 gload_lds16/thread (2 A + 2 B).
  // LDS linear; global source chunk pre-swizzled: chunk = (c&3) ^ (row&3) ^ ((row>>2)&3).
  auto stage = [&](int slot, int kt) {
    int k0 = kt << 5;
    __bf16* dstA = &smem[slot * 8192];
#pragma unroll
    for (int j = 0; j < 2; ++j) {
      int ci = (wid * 2 + j) * 64 + lane;          // chunk index 0..511
      int row = ci >> 2;
      int c = (ci & 3) ^ (row & 3) ^ ((row >> 2) & 3);
      gload_lds16(A  + (size_t)(m0 + row) * K + k0 + c * 8, dstA + (wid * 2 + j) * 512);
      gload_lds16(BT + (size_t)(n0 + row) * K + k0 + c * 8, dstA + 4096 + (wid * 2 + j) * 512);
    }
  };

  int nt = K >> 5;
  stage(0, 0);
  __syncthreads();
  for (int t = 0; t < nt; ++t) {
    int s = t & 1;
    if (t + 1 < nt) stage(s ^ 1, t + 1);           // overlaps with reads+MFMA of tile t
    const __bf16* At = &smem[s * 8192];
    const __bf16* Bt = At + 4096;
    bf8_t av[4], bv[4];
#pragma unroll
    for (int m = 0; m < 4; ++m) {
      int row = wr * 64 + m * 16 + ln15;
      av[m] = *(const bf8_t*)&At[row * 32 + ((kq ^ (row & 3) ^ ((row >> 2) & 3)) << 3)];
    }
#pragma unroll
    for (int n = 0; n < 4; ++n) {
      int row = wc * 64 + n * 16 + ln15;
      bv[n] = *(const bf8_t*)&Bt[row * 32 + ((kq ^ (row & 3) ^ ((row >> 2) & 3)) << 3)];
    }
    __builtin_amdgcn_s_setprio(1);
#pragma unroll
    for (int m = 0; m < 4; ++m)
#pragma unroll
      for (int n = 0; n < 4; ++n)
        acc[m][n] = __builtin_amdgcn_mfma_f32_16x16x32_bf16(av[m], bv[n], acc[m][n], 0, 0, 0);
    __builtin_amdgcn_s_setprio(0);
    __syncthreads();   // drains stage(t+1) writes + reads of slot s
  }

  bool hi = (EPI == 4) && (n0 >= 512);
  const float* bptr = hi ? bias2 : bias;
  int nbase = hi ? n0 - 512 : n0;
  float bs[4];
#pragma unroll
  for (int n = 0; n < 4; ++n) bs[n] = bptr[nbase + wc * 64 + n * 16 + ln15];

  // ---- transform acc in place ----
#pragma unroll
  for (int m = 0; m < 4; ++m) {
    int lr2 = m0 + wr * 64 + m * 16 + kq * 4;
#pragma unroll
    for (int r = 0; r < 4; ++r) {
      int grow = row0 + lr2 + r;
      const float* rptr = nullptr; int so = 0;
      if (EPI == 1) { so = srcoff[grow]; rptr = (grow < XTOK) ? resx : resy; }
#pragma unroll
      for (int n = 0; n < 4; ++n) {
        int gcol = nbase + wc * 64 + n * 16 + ln15;
        float v = acc[m][n][r] + bs[n];
        if (EPI == 1) v += rptr[(size_t)so + gcol];
        if (EPI == 2) v = 0.5f * v * (1.0f + erff(v * 0.7071067811865475f));
        if (EPI == 3) v += toksf[(size_t)grow * DIMC + gcol];
        acc[m][n][r] = v;
      }
    }
  }

  if (EPI == 0 || EPI == 2 || EPI == 4) {
    // bf16 full-tile stage [128][136] -> 256B-contiguous row writes
#pragma unroll
    for (int m = 0; m < 4; ++m)
#pragma unroll
      for (int r = 0; r < 4; ++r)
#pragma unroll
        for (int n = 0; n < 4; ++n)
          smem[(wr * 64 + m * 16 + kq * 4 + r) * 136 + wc * 64 + n * 16 + ln15] = (__bf16)acc[m][n][r];
    __syncthreads();
    __bf16* ob = (EPI == 4 && hi) ? outb2 : outb;
    int ldn = (EPI == 2) ? N : 512;
    int gc0 = (EPI == 2) ? n0 : nbase;
#pragma unroll
    for (int it = 0; it < 8; ++it) {
      int cid = it * 256 + tid;                    // 2048 chunks = 128 rows x 16
      int row = cid >> 4, c = cid & 15;
      i4_t v = *(const i4_t*)&smem[row * 136 + c * 8];
      *(i4_t*)&ob[(size_t)(m0 + row) * ldn + gc0 + c * 8] = v;
    }
  } else {
    // fp32 stage in two 64-col halves [128][68]
    float* stf = (float*)smem;
#pragma unroll
    for (int h = 0; h < 2; ++h) {
      __syncthreads();
      if (wc == h) {
#pragma unroll
        for (int m = 0; m < 4; ++m)
#pragma unroll
          for (int r = 0; r < 4; ++r)
#pragma unroll
            for (int n = 0; n < 4; ++n)
              stf[(wr * 64 + m * 16 + kq * 4 + r) * 68 + n * 16 + ln15] = acc[m][n][r];
      }
      __syncthreads();
#pragma unroll
      for (int it = 0; it < 8; ++it) {
        int cid = it * 256 + tid;
        int row = cid >> 4, c = cid & 15;
        f4_t v = *(const f4_t*)&stf[row * 68 + c * 4];
        if (EPI == 1) {
          size_t grow = (size_t)(m0 + row);
          *(f4_t*)&outf[grow * 512 + n0 + h * 64 + c * 4] = v;
          union { __bf16 b[4]; uint2 u; } pk;
#pragma unroll
          for (int j = 0; j < 4; ++j) pk.b[j] = (__bf16)v[j];
          *(uint2*)&outb[grow * 512 + n0 + h * 64 + c * 4] = pk.u;
        } else {   // EPI 3
          int oo = outoff[row0 + m0 + row];
          *(f4_t*)&dout[(size_t)oo + n0 + h * 64 + c * 4] = v;
        }
      }
    }
  }
}

// ---------------- windowed attention v5: swapped-QK, packed-S, no spill ----------------
__global__ __launch_bounds__(512, 4)
void attn_kernel(const __bf16* __restrict__ Qb, const __bf16* __restrict__ Kb,
                 const __bf16* __restrict__ Vb, __bf16* __restrict__ AOb) {
  __shared__ __align__(16) __bf16 smem[32768];       // Kl[16384] + Vt[16384]
  __bf16* Kl = smem;                                  // chunk16 i = s*8 + (c ^ (s&7))
  __bf16* Vt = smem + 16384;                          // el(d,s) = d*256 + (((s>>3)^(d>>3)^(d&7))<<3) + (s&7)
  int tid = threadIdx.x, lane = tid & 63, wid = tid >> 6;
  int l15 = lane & 15, kq = lane >> 4;
  int win = blockIdx.x >> 3, head = blockIdx.x & 7;
  size_t wtok = (size_t)win * 256;
  int hc = head * 64;

#pragma unroll
  for (int it = 0; it < 4; ++it) {
    int i = (wid * 4 + it) * 64 + lane;
    int s = i >> 3, cp = i & 7, c = cp ^ (s & 7);
    gload_lds16(Kb + (wtok + s) * 512 + hc + c * 8, &Kl[(size_t)((wid * 4 + it) * 64) * 8]);
  }
#pragma unroll
  for (int it = 0; it < 4; ++it) {
    int j = tid + it * 512;
    int dc = j & 7, s = j >> 3;
    i4_t v = *(const i4_t*)(Vb + (wtok + s) * 512 + hc + dc * 8);
    const __bf16* ve = (const __bf16*)&v;
#pragma unroll
    for (int jj = 0; jj < 8; ++jj) {
      int d = dc * 8 + jj;
      int sc = (s >> 3) ^ (((d >> 3) ^ d) & 7);
      Vt[d * 256 + (sc << 3) + (s & 7)] = ve[jj];
    }
  }
  __syncthreads();

  const float CLOG2E = 0.18033688011112043f;        // 0.125 * log2(e)
  f4_t oacc[2][4];
  float rinvq[2];
  int sl0 = ((kq & 1) << 5) + l15;
  int sl1 = sl0 + 16;
  bool hiT = (kq & 2) != 0;

#pragma unroll
  for (int qt = 0; qt < 2; ++qt) {
    int qbase = wid * 32 + qt * 16;
    bf8_t qf[2];
#pragma unroll
    for (int k2 = 0; k2 < 2; ++k2)
      qf[k2] = *(const bf8_t*)(Qb + (wtok + qbase + l15) * 512 + hc + k2 * 32 + kq * 8);

    uint2 ps[16];
    float mx = -3.0e38f;
    __builtin_amdgcn_s_setprio(1);
#pragma unroll
    for (int st = 0; st < 16; ++st) {
      f4_t z = {0.f, 0.f, 0.f, 0.f};
      int s = st * 16 + l15;
#pragma unroll
      for (int k2 = 0; k2 < 2; ++k2) {
        int c = (k2 * 4 + kq) ^ (s & 7);
        bf8_t kf = *(const bf8_t*)&Kl[(s * 8 + c) * 8];
        z = __builtin_amdgcn_mfma_f32_16x16x32_bf16(kf, qf[k2], z, 0, 0, 0);
      }
      z *= CLOG2E;
      mx = fmaxf(mx, fmaxf(fmaxf(z[0], z[1]), fmaxf(z[2], z[3])));
      union { __bf16 b[4]; uint2 u; } pk;
#pragma unroll
      for (int r = 0; r < 4; ++r) pk.b[r] = (__bf16)z[r];
      ps[st] = pk.u;
    }
    __builtin_amdgcn_s_setprio(0);
    mx = fmaxf(mx, __shfl_xor(mx, 16, 64));
    mx = fmaxf(mx, __shfl_xor(mx, 32, 64));

    float L = 0.f;
#pragma unroll
    for (int st = 0; st < 16; ++st) {
      uint2 u = ps[st];
      float p0 = __builtin_amdgcn_exp2f(bflo(u.x) - mx);
      float p1 = __builtin_amdgcn_exp2f(bfhi(u.x) - mx);
      float p2 = __builtin_amdgcn_exp2f(bflo(u.y) - mx);
      float p3 = __builtin_amdgcn_exp2f(bfhi(u.y) - mx);
      L += (p0 + p1) + (p2 + p3);
      union { __bf16 b[4]; uint2 u; } pk;
      pk.b[0] = (__bf16)p0; pk.b[1] = (__bf16)p1; pk.b[2] = (__bf16)p2; pk.b[3] = (__bf16)p3;
      ps[st] = pk.u;
    }
    L += __shfl_xor(L, 16, 64);
    L += __shfl_xor(L, 32, 64);
    rinvq[qt] = 1.0f / L;

#pragma unroll
    for (int dn = 0; dn < 4; ++dn) oacc[qt][dn] = f4_t{0.f, 0.f, 0.f, 0.f};
    __builtin_amdgcn_s_setprio(1);
#pragma unroll
    for (int c = 0; c < 8; ++c) {
      uint2 t0 = ps[2 * c], t1 = ps[2 * c + 1];
      int a00x = __shfl((int)t0.x, sl0, 64), a00y = __shfl((int)t0.y, sl0, 64);
      int a01x = __shfl((int)t0.x, sl1, 64), a01y = __shfl((int)t0.y, sl1, 64);
      int a10x = __shfl((int)t1.x, sl0, 64), a10y = __shfl((int)t1.y, sl0, 64);
      int a11x = __shfl((int)t1.x, sl1, 64), a11y = __shfl((int)t1.y, sl1, 64);
      union { int u[4]; bf8_t v; } fr;
      fr.u[0] = hiT ? a10x : a00x;
      fr.u[1] = hiT ? a10y : a00y;
      fr.u[2] = hiT ? a11x : a01x;
      fr.u[3] = hiT ? a11y : a01y;
#pragma unroll
      for (int dn = 0; dn < 4; ++dn) {
        int d = dn * 16 + l15;
        int sc = (4 * c + kq) ^ (((d >> 3) ^ d) & 7);
        bf8_t vf = *(const bf8_t*)&Vt[d * 256 + (sc << 3)];
        oacc[qt][dn] = __builtin_amdgcn_mfma_f32_16x16x32_bf16(fr.v, vf, oacc[qt][dn], 0, 0, 0);
      }
    }
    __builtin_amdgcn_s_setprio(0);
  }

  __syncthreads();
  __bf16* Ko = smem + wid * 2304;                    // [32][72]
#pragma unroll
  for (int qt = 0; qt < 2; ++qt)
#pragma unroll
    for (int dn = 0; dn < 4; ++dn)
#pragma unroll
      for (int r = 0; r < 4; ++r)
        Ko[(qt * 16 + kq * 4 + r) * 72 + dn * 16 + l15] = (__bf16)(oacc[qt][dn][r] * rinvq[qt]);
#pragma unroll
  for (int it = 0; it < 4; ++it) {
    int lr = it * 8 + (lane >> 3), cb = (lane & 7) * 8;
    i4_t v = *(const i4_t*)&Ko[lr * 72 + cb];
    *(i4_t*)&AOb[(wtok + wid * 32 + lr) * 512 + hc + cb] = v;
  }
}

extern "C" void kernel_launch(void* const* d_in, const int* in_sizes, int n_in,
                              void* d_out, int out_size, void* d_ws, size_t ws_size,
                              hipStream_t stream) {
  const float* x  = (const float*)d_in[0];
  const float* y  = (const float*)d_in[1];
  const float* Wq = (const float*)d_in[2];
  const float* bq = (const float*)d_in[3];
  const float* Wk = (const float*)d_in[4];
  const float* bk = (const float*)d_in[5];
  const float* Wv = (const float*)d_in[6];
  const float* bv = (const float*)d_in[7];
  const float* Wo = (const float*)d_in[8];
  const float* bo = (const float*)d_in[9];
  const float* W1 = (const float*)d_in[10];
  const float* b1 = (const float*)d_in[11];
  const float* W2 = (const float*)d_in[12];
  const float* b2 = (const float*)d_in[13];

  char* ws = (char*)d_ws;
  size_t off = 0;
  auto carve = [&](size_t bytes) -> void* {
    void* p = ws + off;
    off += (bytes + 255) & ~(size_t)255;
    return p;
  };
  __bf16* WqvT = (__bf16*)carve((size_t)1024 * 512 * 2);  // [Wq^T; Wv^T]
  __bf16* WkT  = (__bf16*)carve((size_t)512 * 512 * 2);
  __bf16* WoT  = (__bf16*)carve((size_t)512 * 512 * 2);
  __bf16* W1T  = (__bf16*)carve((size_t)2048 * 512 * 2);
  __bf16* W2T  = (__bf16*)carve((size_t)512 * 2048 * 2);
  int* srcoff = (int*)carve((size_t)NTOK * 4);
  int* outoff = (int*)carve((size_t)NTOK * 4);
  __bf16* Asrc = (__bf16*)carve((size_t)NTOK * 512 * 2);
  __bf16* Aoth = (__bf16*)carve((size_t)NTOK * 512 * 2);
  __bf16* Qb   = (__bf16*)carve((size_t)NTOK * 512 * 2);
  __bf16* Kb   = (__bf16*)carve((size_t)NTOK * 512 * 2);
  __bf16* Vb   = (__bf16*)carve((size_t)NTOK * 512 * 2);
  int nc = 1;
  while (nc < 4 && off + (size_t)(NTOK / nc) * 2048 * 2 > ws_size) nc *= 2;
  int rows = NTOK / nc;
  __bf16* Hb = (__bf16*)carve((size_t)rows * 2048 * 2);
  // aliases (lifetimes: producer of alias runs after last reader of original)
  __bf16* AOb   = Asrc;              // attention out  (Asrc dead after QV-GEMM)
  __bf16* toksb = Aoth;              // tokens bf16    (Aoth dead after K-GEMM)
  float*  toksf = (float*)Kb;        // tokens fp32, spans Kb+Vb (dead after attention)
  float*  dout  = (float*)d_out;

  dim3 tb(256);
  transpose_cast<<<dim3(512 / 32, 512 / 32), tb, 0, stream>>>(Wq, WqvT, 512, 512);
  transpose_cast<<<dim3(512 / 32, 512 / 32), tb, 0, stream>>>(Wv, WqvT + (size_t)512 * 512, 512, 512);
  transpose_cast<<<dim3(512 / 32, 512 / 32), tb, 0, stream>>>(Wk, WkT, 512, 512);
  transpose_cast<<<dim3(512 / 32, 512 / 32), tb, 0, stream>>>(Wo, WoT, 512, 512);
  transpose_cast<<<dim3(2048 / 32, 512 / 32), tb, 0, stream>>>(W1, W1T, 512, 2048);
  transpose_cast<<<dim3(512 / 32, 2048 / 32), tb, 0, stream>>>(W2, W2T, 2048, 512);

  pack_tokens<<<NTOK, 256, 0, stream>>>(x, y, Asrc, Aoth, srcoff, outoff);

  gemm_bt<4><<<NTOK / 128 * 8, 256, 0, stream>>>(Asrc, WqvT, bq, bv, 512, 8, 0, Qb, Vb, nullptr, nullptr, nullptr, nullptr, nullptr, nullptr, nullptr);
  gemm_bt<0><<<NTOK / 128 * 4, 256, 0, stream>>>(Aoth, WkT, bk, nullptr, 512, 4, 0, Kb, nullptr, nullptr, nullptr, nullptr, nullptr, nullptr, nullptr, nullptr);

  attn_kernel<<<160 * 8, 512, 0, stream>>>(Qb, Kb, Vb, AOb);

  gemm_bt<1><<<NTOK / 128 * 4, 256, 0, stream>>>(AOb, WoT, bo, nullptr, 512, 4, 0, toksb, nullptr, toksf, x, y, srcoff, nullptr, nullptr, nullptr);

  for (int c = 0; c < nc; ++c) {
    int r0 = c * rows;
    gemm_bt<2><<<rows / 128 * 16, 256, 0, stream>>>(toksb + (size_t)r0 * 512, W1T, b1, nullptr, 512, 16, r0, Hb, nullptr, nullptr, nullptr, nullptr, nullptr, nullptr, nullptr, nullptr);
    gemm_bt<3><<<rows / 128 * 4, 256, 0, stream>>>(Hb, W2T, b2, nullptr, 2048, 4, r0, nullptr, nullptr, nullptr, nullptr, nullptr, nullptr, outoff, toksf, dout);
  }
}

// Round 13
// 616.392 us; speedup vs baseline: 2.5113x; 1.0208x over previous
//
#include <hip/hip_runtime.h>
#include <hip/hip_bf16.h>
#include <math.h>

typedef __attribute__((ext_vector_type(8))) __bf16 bf8_t;
typedef __attribute__((ext_vector_type(4))) float f4_t;
typedef __attribute__((ext_vector_type(4))) int   i4_t;

#define XTOK 32768
#define NTOK 40960
#define DIMC 512

__device__ __forceinline__ void gload_lds16(const __bf16* g, __bf16* l) {
  __builtin_amdgcn_global_load_lds((const __attribute__((address_space(1))) void*)g,
                                   (__attribute__((address_space(3))) void*)l, 16, 0, 0);
}
__device__ __forceinline__ float bflo(unsigned u) { union { unsigned x; float f; } c; c.x = u << 16; return c.f; }
__device__ __forceinline__ float bfhi(unsigned u) { union { unsigned x; float f; } c; c.x = u & 0xffff0000u; return c.f; }

// exact-enough gelu: erf via Abramowitz-Stegun 7.1.26 (|eps|<1.5e-7, below bf16 ulp)
__device__ __forceinline__ float gelu_fast(float v) {
  float u = v * 0.70710678118654752f;
  float a = fabsf(u);
  float t = 1.0f / (1.0f + 0.3275911f * a);
  float e = __builtin_amdgcn_exp2f(-a * a * 1.4426950408889634f);
  float poly = t * (0.254829592f + t * (-0.284496736f + t * (1.421413741f +
               t * (-1.453152027f + t * 1.061405429f))));
  float erfa = 1.0f - poly * e;
  float erfu = (u < 0.0f) ? -erfa : erfa;
  return 0.5f * v * (1.0f + erfu);
}

// ---------------- merged weight transpose + cast: 6 matrices, one launch ----------------
// WT[n][k] = W[k][n].  Segments (32x32 tiles): 4x 512x512 (256 tiles each), W1 512x2048
// (1024), W2 2048x512 (1024). Total 3072 tile-blocks.
__global__ void transpose_all(const float* __restrict__ Wq, const float* __restrict__ Wv,
                              const float* __restrict__ Wk, const float* __restrict__ Wo,
                              const float* __restrict__ W1, const float* __restrict__ W2,
                              __bf16* __restrict__ WqvT, __bf16* __restrict__ WkT,
                              __bf16* __restrict__ WoT, __bf16* __restrict__ W1T,
                              __bf16* __restrict__ W2T) {
  __shared__ float t[32][33];
  int b = blockIdx.x;
  const float* W; __bf16* WT; int K, N, tb;
  if (b < 256)       { W = Wq; WT = WqvT;                       K = 512;  N = 512;  tb = b; }
  else if (b < 512)  { W = Wv; WT = WqvT + (size_t)512 * 512;   K = 512;  N = 512;  tb = b - 256; }
  else if (b < 768)  { W = Wk; WT = WkT;                        K = 512;  N = 512;  tb = b - 512; }
  else if (b < 1024) { W = Wo; WT = WoT;                        K = 512;  N = 512;  tb = b - 768; }
  else if (b < 2048) { W = W1; WT = W1T;                        K = 512;  N = 2048; tb = b - 1024; }
  else               { W = W2; WT = W2T;                        K = 2048; N = 512;  tb = b - 2048; }
  int ntn = N >> 5;
  int bk = (tb / ntn) * 32, bn = (tb - (tb / ntn) * ntn) * 32;
  int tx = threadIdx.x & 31, ty = threadIdx.x >> 5;   // 32 x 8
#pragma unroll
  for (int i = 0; i < 4; ++i)
    t[ty + i * 8][tx] = W[(size_t)(bk + ty + i * 8) * N + bn + tx];
  __syncthreads();
#pragma unroll
  for (int i = 0; i < 4; ++i)
    WT[(size_t)(bn + ty + i * 8) * K + bk + tx] = (__bf16)t[tx][ty + i * 8];
}

// ---------------- token pack: window-order gather + resize, fp32 -> bf16 ----------------
__global__ void pack_tokens(const float* __restrict__ x, const float* __restrict__ y,
                            __bf16* __restrict__ Asrc, __bf16* __restrict__ Aoth,
                            int* __restrict__ srcoff, int* __restrict__ outoff) {
  int g = blockIdx.x;           // window-ordered token row, 0..40959
  int t = threadIdx.x;          // 256 threads, 2 channels each
  int b, h, w; int soff, ooff; bool isx = (g < XTOK);
  if (isx) {
    b = g >> 12;
    int w5 = g & 4095;
    int widx = w5 >> 8, tt = w5 & 255;
    int wh = widx >> 2, ww = widx & 3;
    h = wh * 16 + (tt >> 4); w = ww * 16 + (tt & 15);
    int n = h * 64 + w;
    soff = (b * 4096 + n) * 512;
    ooff = (b * 5120 + n) * 512;
  } else {
    int gy = g - XTOK;
    b = gy >> 10;
    int w5 = gy & 1023;
    int widx = w5 >> 8, tt = w5 & 255;
    int wh = widx >> 1, ww = widx & 1;
    h = wh * 16 + (tt >> 4); w = ww * 16 + (tt & 15);
    int n = h * 32 + w;
    soff = (b * 1024 + n) * 512;
    ooff = (b * 5120 + 4096 + n) * 512;
  }
  if (t == 0) { srcoff[g] = soff; outoff[g] = ooff; }
  const float* sp = (isx ? x : y) + (size_t)soff + t * 2;
  float2 sv = *(const float2*)sp;
  size_t gb = (size_t)g * 512 + t * 2;
  Asrc[gb]     = (__bf16)sv.x;
  Asrc[gb + 1] = (__bf16)sv.y;

  float o0, o1;
  if (isx) {
    // bilinear upsample 32x32 -> 64x64, half-pixel centers, edge clamp
    int h0, h1, w0i, w1i; float fh0, fh1, fw0, fw1;
    if (h & 1) { h0 = h >> 1; h1 = (h0 + 1 < 31) ? h0 + 1 : 31; fh0 = 0.75f; fh1 = 0.25f; }
    else       { h1 = h >> 1; h0 = (h1 - 1 > 0) ? h1 - 1 : 0;   fh0 = 0.25f; fh1 = 0.75f; }
    if (w & 1) { w0i = w >> 1; w1i = (w0i + 1 < 31) ? w0i + 1 : 31; fw0 = 0.75f; fw1 = 0.25f; }
    else       { w1i = w >> 1; w0i = (w1i - 1 > 0) ? w1i - 1 : 0;   fw0 = 0.25f; fw1 = 0.75f; }
    const float* yb = y + (size_t)b * 1024 * 512 + t * 2;
    float2 v00 = *(const float2*)(yb + (h0 * 32 + w0i) * 512);
    float2 v01 = *(const float2*)(yb + (h0 * 32 + w1i) * 512);
    float2 v10 = *(const float2*)(yb + (h1 * 32 + w0i) * 512);
    float2 v11 = *(const float2*)(yb + (h1 * 32 + w1i) * 512);
    o0 = fh0 * (fw0 * v00.x + fw1 * v01.x) + fh1 * (fw0 * v10.x + fw1 * v11.x);
    o1 = fh0 * (fw0 * v00.y + fw1 * v01.y) + fh1 * (fw0 * v10.y + fw1 * v11.y);
  } else {
    // bilinear downsample 64x64 -> 32x32 == 2x2 average pool
    const float* xb = x + (size_t)b * 4096 * 512 + t * 2;
    float2 v00 = *(const float2*)(xb + ((2 * h) * 64 + 2 * w) * 512);
    float2 v01 = *(const float2*)(xb + ((2 * h) * 64 + 2 * w + 1) * 512);
    float2 v10 = *(const float2*)(xb + ((2 * h + 1) * 64 + 2 * w) * 512);
    float2 v11 = *(const float2*)(xb + ((2 * h + 1) * 64 + 2 * w + 1) * 512);
    o0 = 0.25f * (v00.x + v01.x + v10.x + v11.x);
    o1 = 0.25f * (v00.y + v01.y + v10.y + v11.y);
  }
  Aoth[gb]     = (__bf16)o0;
  Aoth[gb + 1] = (__bf16)o1;
}

// ---------------- GEMM v8b: 128^2 tile, BK=32, 2-slot dbuf, 1 barrier/K-step ----------------
// Identical frame to R12 (passed, 629us). bf16-only outputs except EPI3 (fp32 d_out).
// EPI 0: out bf16 = acc + bias                     (K-proj)
// EPI 1: out bf16 = acc + bias + residual(fp32 src gather)   (Wo -> toksb)
// EPI 2: out bf16 = gelu_fast(acc + bias)          (MLP1)
// EPI 3: fp32 dout at permuted offset = acc + bias + (float)toksb   (MLP2)
// EPI 4: fused QV: n0<512 -> outb (Q, bias), else outb2 (V, bias2)
template<int EPI>
__global__ __launch_bounds__(256, 2)
void gemm_bt(const __bf16* __restrict__ A, const __bf16* __restrict__ BT,
             const float* __restrict__ bias, const float* __restrict__ bias2,
             int K, int nbn, int row0,
             __bf16* __restrict__ outb, __bf16* __restrict__ outb2,
             const float* __restrict__ resx, const float* __restrict__ resy,
             const int* __restrict__ srcoff, const int* __restrict__ outoff,
             const __bf16* __restrict__ toksr, float* __restrict__ dout) {
  const int N = nbn * 128;
  __shared__ __align__(16) __bf16 smem[17408];     // 34816B: 2 slots x 8192 el; epilogue reuse
  // bijective XCD swizzle (m204): contiguous m-major chunk per XCD
  int nwg = gridDim.x;
  int qq = nwg >> 3, rr = nwg & 7;
  int xcd = blockIdx.x & 7, base = blockIdx.x >> 3;
  int wg = (xcd < rr ? xcd * (qq + 1) : rr * (qq + 1) + (xcd - rr) * qq) + base;
  int bm = wg / nbn, bn = wg - bm * nbn;
  int m0 = bm * 128, n0 = bn * 128;

  int tid = threadIdx.x, lane = tid & 63, wid = tid >> 6;
  int wr = wid >> 1, wc = wid & 1;
  int ln15 = lane & 15, kq = lane >> 4;

  f4_t acc[4][4];
#pragma unroll
  for (int m = 0; m < 4; ++m)
#pragma unroll
    for (int n = 0; n < 4; ++n) acc[m][n] = f4_t{0.f, 0.f, 0.f, 0.f};

  // stage K-tile kt into slot. 4 gload_lds16/thread (2 A + 2 B).
  // LDS linear; global source chunk pre-swizzled: chunk = (c&3) ^ (row&3) ^ ((row>>2)&3).
  auto stage = [&](int slot, int kt) {
    int k0 = kt << 5;
    __bf16* dstA = &smem[slot * 8192];
#pragma unroll
    for (int j = 0; j < 2; ++j) {
      int ci = (wid * 2 + j) * 64 + lane;          // chunk index 0..511
      int row = ci >> 2;
      int c = (ci & 3) ^ (row & 3) ^ ((row >> 2) & 3);
      gload_lds16(A  + (size_t)(m0 + row) * K + k0 + c * 8, dstA + (wid * 2 + j) * 512);
      gload_lds16(BT + (size_t)(n0 + row) * K + k0 + c * 8, dstA + 4096 + (wid * 2 + j) * 512);
    }
  };

  int nt = K >> 5;
  stage(0, 0);
  __syncthreads();
  for (int t = 0; t < nt; ++t) {
    int s = t & 1;
    if (t + 1 < nt) stage(s ^ 1, t + 1);           // overlaps with reads+MFMA of tile t
    const __bf16* At = &smem[s * 8192];
    const __bf16* Bt = At + 4096;
    bf8_t av[4], bv[4];
#pragma unroll
    for (int m = 0; m < 4; ++m) {
      int row = wr * 64 + m * 16 + ln15;
      av[m] = *(const bf8_t*)&At[row * 32 + ((kq ^ (row & 3) ^ ((row >> 2) & 3)) << 3)];
    }
#pragma unroll
    for (int n = 0; n < 4; ++n) {
      int row = wc * 64 + n * 16 + ln15;
      bv[n] = *(const bf8_t*)&Bt[row * 32 + ((kq ^ (row & 3) ^ ((row >> 2) & 3)) << 3)];
    }
    __builtin_amdgcn_s_setprio(1);
#pragma unroll
    for (int m = 0; m < 4; ++m)
#pragma unroll
      for (int n = 0; n < 4; ++n)
        acc[m][n] = __builtin_amdgcn_mfma_f32_16x16x32_bf16(av[m], bv[n], acc[m][n], 0, 0, 0);
    __builtin_amdgcn_s_setprio(0);
    __syncthreads();   // drains stage(t+1) writes + reads of slot s
  }

  bool hi = (EPI == 4) && (n0 >= 512);
  const float* bptr = hi ? bias2 : bias;
  int nbase = hi ? n0 - 512 : n0;
  float bs[4];
#pragma unroll
  for (int n = 0; n < 4; ++n) bs[n] = bptr[nbase + wc * 64 + n * 16 + ln15];

  // ---- transform acc in place ----
#pragma unroll
  for (int m = 0; m < 4; ++m) {
    int lr2 = m0 + wr * 64 + m * 16 + kq * 4;
#pragma unroll
    for (int r = 0; r < 4; ++r) {
      int grow = row0 + lr2 + r;
      const float* rptr = nullptr; int so = 0;
      if (EPI == 1) { so = srcoff[grow]; rptr = (grow < XTOK) ? resx : resy; }
#pragma unroll
      for (int n = 0; n < 4; ++n) {
        int gcol = nbase + wc * 64 + n * 16 + ln15;
        float v = acc[m][n][r] + bs[n];
        if (EPI == 1) v += rptr[(size_t)so + gcol];
        if (EPI == 2) v = gelu_fast(v);
        if (EPI == 3) v += (float)toksr[(size_t)grow * DIMC + gcol];
        acc[m][n][r] = v;
      }
    }
  }

  if (EPI != 3) {
    // bf16 full-tile stage [128][136] -> 256B-contiguous row writes
#pragma unroll
    for (int m = 0; m < 4; ++m)
#pragma unroll
      for (int r = 0; r < 4; ++r)
#pragma unroll
        for (int n = 0; n < 4; ++n)
          smem[(wr * 64 + m * 16 + kq * 4 + r) * 136 + wc * 64 + n * 16 + ln15] = (__bf16)acc[m][n][r];
    __syncthreads();
    __bf16* ob = (EPI == 4 && hi) ? outb2 : outb;
    int ldn = (EPI == 2) ? N : 512;
    int gc0 = (EPI == 2) ? n0 : nbase;
#pragma unroll
    for (int it = 0; it < 8; ++it) {
      int cid = it * 256 + tid;                    // 2048 chunks = 128 rows x 16
      int row = cid >> 4, c = cid & 15;
      i4_t v = *(const i4_t*)&smem[row * 136 + c * 8];
      *(i4_t*)&ob[(size_t)(m0 + row) * ldn + gc0 + c * 8] = v;
    }
  } else {
    // fp32 stage in two 64-col halves [128][68] -> permuted-row d_out writes
    float* stf = (float*)smem;
#pragma unroll
    for (int h = 0; h < 2; ++h) {
      __syncthreads();
      if (wc == h) {
#pragma unroll
        for (int m = 0; m < 4; ++m)
#pragma unroll
          for (int r = 0; r < 4; ++r)
#pragma unroll
            for (int n = 0; n < 4; ++n)
              stf[(wr * 64 + m * 16 + kq * 4 + r) * 68 + n * 16 + ln15] = acc[m][n][r];
      }
      __syncthreads();
#pragma unroll
      for (int it = 0; it < 8; ++it) {
        int cid = it * 256 + tid;
        int row = cid >> 4, c = cid & 15;
        f4_t v = *(const f4_t*)&stf[row * 68 + c * 4];
        int oo = outoff[row0 + m0 + row];
        *(f4_t*)&dout[(size_t)oo + n0 + h * 64 + c * 4] = v;
      }
    }
  }
}

// ---------------- windowed attention v6: swapped-QK, K from L2, LDS 36.9KB ----------------
// 512 thr / 8 waves. K-fragments read straight from global (L2/HBM, one 128B line per row
// per head) instead of LDS staging -> LDS = Vt only (32KB) + O-stage overlay (36.9KB total),
// allowing up to 4 blocks/CU when register use permits.
__global__ __launch_bounds__(512, 4)
void attn_kernel(const __bf16* __restrict__ Qb, const __bf16* __restrict__ Kb,
                 const __bf16* __restrict__ Vb, __bf16* __restrict__ AOb) {
  __shared__ __align__(16) __bf16 smem[18432];       // Vt[16384]; O-stage overlay [18432]
  __bf16* Vt = smem;                                  // el(d,s) = d*256 + (((s>>3)^(d>>3)^(d&7))<<3) + (s&7)
  int tid = threadIdx.x, lane = tid & 63, wid = tid >> 6;
  int l15 = lane & 15, kq = lane >> 4;
  int win = blockIdx.x >> 3, head = blockIdx.x & 7;
  size_t wtok = (size_t)win * 256;
  int hc = head * 64;

  // ---- stage V d-major swizzled (reg scatter, conflict-free) ----
#pragma unroll
  for (int it = 0; it < 4; ++it) {
    int j = tid + it * 512;
    int dc = j & 7, s = j >> 3;
    i4_t v = *(const i4_t*)(Vb + (wtok + s) * 512 + hc + dc * 8);
    const __bf16* ve = (const __bf16*)&v;
#pragma unroll
    for (int jj = 0; jj < 8; ++jj) {
      int d = dc * 8 + jj;
      int sc = (s >> 3) ^ (((d >> 3) ^ d) & 7);
      Vt[d * 256 + (sc << 3) + (s & 7)] = ve[jj];
    }
  }
  __syncthreads();

  const __bf16* kwb = Kb + wtok * 512 + hc;          // uniform base for K-frag loads
  const float CLOG2E = 0.18033688011112043f;        // 0.125 * log2(e)
  f4_t oacc[2][4];
  float rinvq[2];
  int sl0 = ((kq & 1) << 5) + l15;
  int sl1 = sl0 + 16;
  bool hiT = (kq & 2) != 0;

#pragma unroll
  for (int qt = 0; qt < 2; ++qt) {
    int qbase = wid * 32 + qt * 16;
    bf8_t qf[2];
#pragma unroll
    for (int k2 = 0; k2 < 2; ++k2)
      qf[k2] = *(const bf8_t*)(Qb + (wtok + qbase + l15) * 512 + hc + k2 * 32 + kq * 8);

    uint2 ps[16];
    float mx = -3.0e38f;
    __builtin_amdgcn_s_setprio(1);
#pragma unroll
    for (int st = 0; st < 16; ++st) {
      f4_t z = {0.f, 0.f, 0.f, 0.f};
      int s = st * 16 + l15;
#pragma unroll
      for (int k2 = 0; k2 < 2; ++k2) {
        bf8_t kf = *(const bf8_t*)(kwb + (size_t)s * 512 + k2 * 32 + kq * 8);
        z = __builtin_amdgcn_mfma_f32_16x16x32_bf16(kf, qf[k2], z, 0, 0, 0);
      }
      z *= CLOG2E;
      mx = fmaxf(mx, fmaxf(fmaxf(z[0], z[1]), fmaxf(z[2], z[3])));
      union { __bf16 b[4]; uint2 u; } pk;
#pragma unroll
      for (int r = 0; r < 4; ++r) pk.b[r] = (__bf16)z[r];
      ps[st] = pk.u;
    }
    __builtin_amdgcn_s_setprio(0);
    mx = fmaxf(mx, __shfl_xor(mx, 16, 64));
    mx = fmaxf(mx, __shfl_xor(mx, 32, 64));

    float L = 0.f;
#pragma unroll
    for (int st = 0; st < 16; ++st) {
      uint2 u = ps[st];
      float p0 = __builtin_amdgcn_exp2f(bflo(u.x) - mx);
      float p1 = __builtin_amdgcn_exp2f(bfhi(u.x) - mx);
      float p2 = __builtin_amdgcn_exp2f(bflo(u.y) - mx);
      float p3 = __builtin_amdgcn_exp2f(bfhi(u.y) - mx);
      L += (p0 + p1) + (p2 + p3);
      union { __bf16 b[4]; uint2 u; } pk;
      pk.b[0] = (__bf16)p0; pk.b[1] = (__bf16)p1; pk.b[2] = (__bf16)p2; pk.b[3] = (__bf16)p3;
      ps[st] = pk.u;
    }
    L += __shfl_xor(L, 16, 64);
    L += __shfl_xor(L, 32, 64);
    rinvq[qt] = 1.0f / L;

#pragma unroll
    for (int dn = 0; dn < 4; ++dn) oacc[qt][dn] = f4_t{0.f, 0.f, 0.f, 0.f};
    __builtin_amdgcn_s_setprio(1);
#pragma unroll
    for (int c = 0; c < 8; ++c) {
      uint2 t0 = ps[2 * c], t1 = ps[2 * c + 1];
      int a00x = __shfl((int)t0.x, sl0, 64), a00y = __shfl((int)t0.y, sl0, 64);
      int a01x = __shfl((int)t0.x, sl1, 64), a01y = __shfl((int)t0.y, sl1, 64);
      int a10x = __shfl((int)t1.x, sl0, 64), a10y = __shfl((int)t1.y, sl0, 64);
      int a11x = __shfl((int)t1.x, sl1, 64), a11y = __shfl((int)t1.y, sl1, 64);
      union { int u[4]; bf8_t v; } fr;
      fr.u[0] = hiT ? a10x : a00x;
      fr.u[1] = hiT ? a10y : a00y;
      fr.u[2] = hiT ? a11x : a01x;
      fr.u[3] = hiT ? a11y : a01y;
#pragma unroll
      for (int dn = 0; dn < 4; ++dn) {
        int d = dn * 16 + l15;
        int sc = (4 * c + kq) ^ (((d >> 3) ^ d) & 7);
        bf8_t vf = *(const bf8_t*)&Vt[d * 256 + (sc << 3)];
        oacc[qt][dn] = __builtin_amdgcn_mfma_f32_16x16x32_bf16(fr.v, vf, oacc[qt][dn], 0, 0, 0);
      }
    }
    __builtin_amdgcn_s_setprio(0);
  }

  // ---- stage O per wave into smem overlay, then coalesced 128-B row writes ----
  __syncthreads();                                   // all waves done with Vt
  __bf16* Ko = smem + wid * 2304;                    // [32][72], 8 waves = 18432 el
#pragma unroll
  for (int qt = 0; qt < 2; ++qt)
#pragma unroll
    for (int dn = 0; dn < 4; ++dn)
#pragma unroll
      for (int r = 0; r < 4; ++r)
        Ko[(qt * 16 + kq * 4 + r) * 72 + dn * 16 + l15] = (__bf16)(oacc[qt][dn][r] * rinvq[qt]);
#pragma unroll
  for (int it = 0; it < 4; ++it) {
    int lr = it * 8 + (lane >> 3), cb = (lane & 7) * 8;
    i4_t v = *(const i4_t*)&Ko[lr * 72 + cb];
    *(i4_t*)&AOb[(wtok + wid * 32 + lr) * 512 + hc + cb] = v;
  }
}

extern "C" void kernel_launch(void* const* d_in, const int* in_sizes, int n_in,
                              void* d_out, int out_size, void* d_ws, size_t ws_size,
                              hipStream_t stream) {
  const float* x  = (const float*)d_in[0];
  const float* y  = (const float*)d_in[1];
  const float* Wq = (const float*)d_in[2];
  const float* bq = (const float*)d_in[3];
  const float* Wk = (const float*)d_in[4];
  const float* bk = (const float*)d_in[5];
  const float* Wv = (const float*)d_in[6];
  const float* bv = (const float*)d_in[7];
  const float* Wo = (const float*)d_in[8];
  const float* bo = (const float*)d_in[9];
  const float* W1 = (const float*)d_in[10];
  const float* b1 = (const float*)d_in[11];
  const float* W2 = (const float*)d_in[12];
  const float* b2 = (const float*)d_in[13];

  char* ws = (char*)d_ws;
  size_t off = 0;
  auto carve = [&](size_t bytes) -> void* {
    void* p = ws + off;
    off += (bytes + 255) & ~(size_t)255;
    return p;
  };
  __bf16* WqvT = (__bf16*)carve((size_t)1024 * 512 * 2);  // [Wq^T; Wv^T]
  __bf16* WkT  = (__bf16*)carve((size_t)512 * 512 * 2);
  __bf16* WoT  = (__bf16*)carve((size_t)512 * 512 * 2);
  __bf16* W1T  = (__bf16*)carve((size_t)2048 * 512 * 2);
  __bf16* W2T  = (__bf16*)carve((size_t)512 * 2048 * 2);
  int* srcoff = (int*)carve((size_t)NTOK * 4);
  int* outoff = (int*)carve((size_t)NTOK * 4);
  __bf16* Asrc = (__bf16*)carve((size_t)NTOK * 512 * 2);
  __bf16* Aoth = (__bf16*)carve((size_t)NTOK * 512 * 2);
  __bf16* Qb   = (__bf16*)carve((size_t)NTOK * 512 * 2);
  __bf16* Kb   = (__bf16*)carve((size_t)NTOK * 512 * 2);
  __bf16* Vb   = (__bf16*)carve((size_t)NTOK * 512 * 2);
  int nc = 1;
  while (nc < 4 && off + (size_t)(NTOK / nc) * 2048 * 2 > ws_size) nc *= 2;
  int rows = NTOK / nc;
  __bf16* Hb = (__bf16*)carve((size_t)rows * 2048 * 2);
  // aliases (lifetimes: producer of alias runs after last reader of original)
  __bf16* AOb   = Asrc;              // attention out  (Asrc dead after QV-GEMM)
  __bf16* toksb = Aoth;              // tokens bf16    (Aoth dead after K-GEMM)
  float*  dout  = (float*)d_out;

  transpose_all<<<3072, 256, 0, stream>>>(Wq, Wv, Wk, Wo, W1, W2, WqvT, WkT, WoT, W1T, W2T);

  pack_tokens<<<NTOK, 256, 0, stream>>>(x, y, Asrc, Aoth, srcoff, outoff);

  gemm_bt<4><<<NTOK / 128 * 8, 256, 0, stream>>>(Asrc, WqvT, bq, bv, 512, 8, 0, Qb, Vb, nullptr, nullptr, nullptr, nullptr, nullptr, nullptr);
  gemm_bt<0><<<NTOK / 128 * 4, 256, 0, stream>>>(Aoth, WkT, bk, nullptr, 512, 4, 0, Kb, nullptr, nullptr, nullptr, nullptr, nullptr, nullptr, nullptr);

  attn_kernel<<<160 * 8, 512, 0, stream>>>(Qb, Kb, Vb, AOb);

  gemm_bt<1><<<NTOK / 128 * 4, 256, 0, stream>>>(AOb, WoT, bo, nullptr, 512, 4, 0, toksb, nullptr, x, y, srcoff, nullptr, nullptr, nullptr);

  for (int c = 0; c < nc; ++c) {
    int r0 = c * rows;
    gemm_bt<2><<<rows / 128 * 16, 256, 0, stream>>>(toksb + (size_t)r0 * 512, W1T, b1, nullptr, 512, 16, r0, Hb, nullptr, nullptr, nullptr, nullptr, nullptr, nullptr, nullptr);
    gemm_bt<3><<<rows / 128 * 4, 256, 0, stream>>>(Hb, W2T, b2, nullptr, 2048, 4, r0, nullptr, nullptr, nullptr, nullptr, nullptr, outoff, toksb, dout);
  }
}

// Round 14
// 572.885 us; speedup vs baseline: 2.7020x; 1.0759x over previous
//
#include <hip/hip_runtime.h>
#include <hip/hip_bf16.h>
#include <math.h>

typedef __attribute__((ext_vector_type(8))) __bf16 bf8_t;
typedef __attribute__((ext_vector_type(4))) float f4_t;
typedef __attribute__((ext_vector_type(4))) int   i4_t;

#define XTOK 32768
#define NTOK 40960
#define DIMC 512

__device__ __forceinline__ void gload_lds16(const __bf16* g, __bf16* l) {
  __builtin_amdgcn_global_load_lds((const __attribute__((address_space(1))) void*)g,
                                   (__attribute__((address_space(3))) void*)l, 16, 0, 0);
}
__device__ __forceinline__ float bflo(unsigned u) { union { unsigned x; float f; } c; c.x = u << 16; return c.f; }
__device__ __forceinline__ float bfhi(unsigned u) { union { unsigned x; float f; } c; c.x = u & 0xffff0000u; return c.f; }

// exact-enough gelu: erf via Abramowitz-Stegun 7.1.26 (|eps|<1.5e-7, below bf16 ulp)
__device__ __forceinline__ float gelu_fast(float v) {
  float u = v * 0.70710678118654752f;
  float a = fabsf(u);
  float t = 1.0f / (1.0f + 0.3275911f * a);
  float e = __builtin_amdgcn_exp2f(-a * a * 1.4426950408889634f);
  float poly = t * (0.254829592f + t * (-0.284496736f + t * (1.421413741f +
               t * (-1.453152027f + t * 1.061405429f))));
  float erfa = 1.0f - poly * e;
  float erfu = (u < 0.0f) ? -erfa : erfa;
  return 0.5f * v * (1.0f + erfu);
}

// ---------------- merged weight transpose + cast: 6 matrices, one launch ----------------
__global__ void transpose_all(const float* __restrict__ Wq, const float* __restrict__ Wv,
                              const float* __restrict__ Wk, const float* __restrict__ Wo,
                              const float* __restrict__ W1, const float* __restrict__ W2,
                              __bf16* __restrict__ WqvT, __bf16* __restrict__ WkT,
                              __bf16* __restrict__ WoT, __bf16* __restrict__ W1T,
                              __bf16* __restrict__ W2T) {
  __shared__ float t[32][33];
  int b = blockIdx.x;
  const float* W; __bf16* WT; int K, N, tb;
  if (b < 256)       { W = Wq; WT = WqvT;                       K = 512;  N = 512;  tb = b; }
  else if (b < 512)  { W = Wv; WT = WqvT + (size_t)512 * 512;   K = 512;  N = 512;  tb = b - 256; }
  else if (b < 768)  { W = Wk; WT = WkT;                        K = 512;  N = 512;  tb = b - 512; }
  else if (b < 1024) { W = Wo; WT = WoT;                        K = 512;  N = 512;  tb = b - 768; }
  else if (b < 2048) { W = W1; WT = W1T;                        K = 512;  N = 2048; tb = b - 1024; }
  else               { W = W2; WT = W2T;                        K = 2048; N = 512;  tb = b - 2048; }
  int ntn = N >> 5;
  int bk = (tb / ntn) * 32, bn = (tb - (tb / ntn) * ntn) * 32;
  int tx = threadIdx.x & 31, ty = threadIdx.x >> 5;   // 32 x 8
#pragma unroll
  for (int i = 0; i < 4; ++i)
    t[ty + i * 8][tx] = W[(size_t)(bk + ty + i * 8) * N + bn + tx];
  __syncthreads();
#pragma unroll
  for (int i = 0; i < 4; ++i)
    WT[(size_t)(bn + ty + i * 8) * K + bk + tx] = (__bf16)t[tx][ty + i * 8];
}

// ---------------- token pack: window-order gather + resize, fp32 -> bf16 ----------------
__global__ void pack_tokens(const float* __restrict__ x, const float* __restrict__ y,
                            __bf16* __restrict__ Asrc, __bf16* __restrict__ Aoth,
                            int* __restrict__ srcoff, int* __restrict__ outoff) {
  int g = blockIdx.x;           // window-ordered token row, 0..40959
  int t = threadIdx.x;          // 256 threads, 2 channels each
  int b, h, w; int soff, ooff; bool isx = (g < XTOK);
  if (isx) {
    b = g >> 12;
    int w5 = g & 4095;
    int widx = w5 >> 8, tt = w5 & 255;
    int wh = widx >> 2, ww = widx & 3;
    h = wh * 16 + (tt >> 4); w = ww * 16 + (tt & 15);
    int n = h * 64 + w;
    soff = (b * 4096 + n) * 512;
    ooff = (b * 5120 + n) * 512;
  } else {
    int gy = g - XTOK;
    b = gy >> 10;
    int w5 = gy & 1023;
    int widx = w5 >> 8, tt = w5 & 255;
    int wh = widx >> 1, ww = widx & 1;
    h = wh * 16 + (tt >> 4); w = ww * 16 + (tt & 15);
    int n = h * 32 + w;
    soff = (b * 1024 + n) * 512;
    ooff = (b * 5120 + 4096 + n) * 512;
  }
  if (t == 0) { srcoff[g] = soff; outoff[g] = ooff; }
  const float* sp = (isx ? x : y) + (size_t)soff + t * 2;
  float2 sv = *(const float2*)sp;
  size_t gb = (size_t)g * 512 + t * 2;
  Asrc[gb]     = (__bf16)sv.x;
  Asrc[gb + 1] = (__bf16)sv.y;

  float o0, o1;
  if (isx) {
    // bilinear upsample 32x32 -> 64x64, half-pixel centers, edge clamp
    int h0, h1, w0i, w1i; float fh0, fh1, fw0, fw1;
    if (h & 1) { h0 = h >> 1; h1 = (h0 + 1 < 31) ? h0 + 1 : 31; fh0 = 0.75f; fh1 = 0.25f; }
    else       { h1 = h >> 1; h0 = (h1 - 1 > 0) ? h1 - 1 : 0;   fh0 = 0.25f; fh1 = 0.75f; }
    if (w & 1) { w0i = w >> 1; w1i = (w0i + 1 < 31) ? w0i + 1 : 31; fw0 = 0.75f; fw1 = 0.25f; }
    else       { w1i = w >> 1; w0i = (w1i - 1 > 0) ? w1i - 1 : 0;   fw0 = 0.25f; fw1 = 0.75f; }
    const float* yb = y + (size_t)b * 1024 * 512 + t * 2;
    float2 v00 = *(const float2*)(yb + (h0 * 32 + w0i) * 512);
    float2 v01 = *(const float2*)(yb + (h0 * 32 + w1i) * 512);
    float2 v10 = *(const float2*)(yb + (h1 * 32 + w0i) * 512);
    float2 v11 = *(const float2*)(yb + (h1 * 32 + w1i) * 512);
    o0 = fh0 * (fw0 * v00.x + fw1 * v01.x) + fh1 * (fw0 * v10.x + fw1 * v11.x);
    o1 = fh0 * (fw0 * v00.y + fw1 * v01.y) + fh1 * (fw0 * v10.y + fw1 * v11.y);
  } else {
    // bilinear downsample 64x64 -> 32x32 == 2x2 average pool
    const float* xb = x + (size_t)b * 4096 * 512 + t * 2;
    float2 v00 = *(const float2*)(xb + ((2 * h) * 64 + 2 * w) * 512);
    float2 v01 = *(const float2*)(xb + ((2 * h) * 64 + 2 * w + 1) * 512);
    float2 v10 = *(const float2*)(xb + ((2 * h + 1) * 64 + 2 * w) * 512);
    float2 v11 = *(const float2*)(xb + ((2 * h + 1) * 64 + 2 * w + 1) * 512);
    o0 = 0.25f * (v00.x + v01.x + v10.x + v11.x);
    o1 = 0.25f * (v00.y + v01.y + v10.y + v11.y);
  }
  Aoth[gb]     = (__bf16)o0;
  Aoth[gb + 1] = (__bf16)o1;
}

// ---------------- GEMM v8b: 128^2 tile, BK=32, 2-slot dbuf, 1 barrier/K-step ----------------
// EPI 0: out bf16 = acc + bias                     (K-proj)
// EPI 1: out bf16 = acc + bias + residual(fp32 src gather)   (Wo -> toksb)
// EPI 2: out bf16 = gelu_fast(acc + bias)          (MLP1)
// EPI 3: fp32 dout at permuted offset = acc + bias + (float)toksb   (MLP2)
// EPI 4: fused QV: n0<512 -> outb (Q, bias), else outb2 (V, bias2)
template<int EPI>
__global__ __launch_bounds__(256, 2)
void gemm_bt(const __bf16* __restrict__ A, const __bf16* __restrict__ BT,
             const float* __restrict__ bias, const float* __restrict__ bias2,
             int K, int nbn, int row0,
             __bf16* __restrict__ outb, __bf16* __restrict__ outb2,
             const float* __restrict__ resx, const float* __restrict__ resy,
             const int* __restrict__ srcoff, const int* __restrict__ outoff,
             const __bf16* __restrict__ toksr, float* __restrict__ dout) {
  const int N = nbn * 128;
  __shared__ __align__(16) __bf16 smem[17408];     // 34816B: 2 slots x 8192 el; epilogue reuse
  // bijective XCD swizzle (m204): contiguous m-major chunk per XCD
  int nwg = gridDim.x;
  int qq = nwg >> 3, rr = nwg & 7;
  int xcd = blockIdx.x & 7, base = blockIdx.x >> 3;
  int wg = (xcd < rr ? xcd * (qq + 1) : rr * (qq + 1) + (xcd - rr) * qq) + base;
  int bm = wg / nbn, bn = wg - bm * nbn;
  int m0 = bm * 128, n0 = bn * 128;

  int tid = threadIdx.x, lane = tid & 63, wid = tid >> 6;
  int wr = wid >> 1, wc = wid & 1;
  int ln15 = lane & 15, kq = lane >> 4;

  f4_t acc[4][4];
#pragma unroll
  for (int m = 0; m < 4; ++m)
#pragma unroll
    for (int n = 0; n < 4; ++n) acc[m][n] = f4_t{0.f, 0.f, 0.f, 0.f};

  // stage K-tile kt into slot. 4 gload_lds16/thread (2 A + 2 B).
  // LDS linear; global source chunk pre-swizzled: chunk = (c&3) ^ (row&3) ^ ((row>>2)&3).
  auto stage = [&](int slot, int kt) {
    int k0 = kt << 5;
    __bf16* dstA = &smem[slot * 8192];
#pragma unroll
    for (int j = 0; j < 2; ++j) {
      int ci = (wid * 2 + j) * 64 + lane;          // chunk index 0..511
      int row = ci >> 2;
      int c = (ci & 3) ^ (row & 3) ^ ((row >> 2) & 3);
      gload_lds16(A  + (size_t)(m0 + row) * K + k0 + c * 8, dstA + (wid * 2 + j) * 512);
      gload_lds16(BT + (size_t)(n0 + row) * K + k0 + c * 8, dstA + 4096 + (wid * 2 + j) * 512);
    }
  };

  int nt = K >> 5;
  stage(0, 0);
  __syncthreads();
  for (int t = 0; t < nt; ++t) {
    int s = t & 1;
    if (t + 1 < nt) stage(s ^ 1, t + 1);           // overlaps with reads+MFMA of tile t
    const __bf16* At = &smem[s * 8192];
    const __bf16* Bt = At + 4096;
    bf8_t av[4], bv[4];
#pragma unroll
    for (int m = 0; m < 4; ++m) {
      int row = wr * 64 + m * 16 + ln15;
      av[m] = *(const bf8_t*)&At[row * 32 + ((kq ^ (row & 3) ^ ((row >> 2) & 3)) << 3)];
    }
#pragma unroll
    for (int n = 0; n < 4; ++n) {
      int row = wc * 64 + n * 16 + ln15;
      bv[n] = *(const bf8_t*)&Bt[row * 32 + ((kq ^ (row & 3) ^ ((row >> 2) & 3)) << 3)];
    }
    __builtin_amdgcn_s_setprio(1);
#pragma unroll
    for (int m = 0; m < 4; ++m)
#pragma unroll
      for (int n = 0; n < 4; ++n)
        acc[m][n] = __builtin_amdgcn_mfma_f32_16x16x32_bf16(av[m], bv[n], acc[m][n], 0, 0, 0);
    __builtin_amdgcn_s_setprio(0);
    __syncthreads();   // drains stage(t+1) writes + reads of slot s
  }

  bool hi = (EPI == 4) && (n0 >= 512);
  const float* bptr = hi ? bias2 : bias;
  int nbase = hi ? n0 - 512 : n0;
  float bs[4];
#pragma unroll
  for (int n = 0; n < 4; ++n) bs[n] = bptr[nbase + wc * 64 + n * 16 + ln15];

  // ---- transform acc in place ----
#pragma unroll
  for (int m = 0; m < 4; ++m) {
    int lr2 = m0 + wr * 64 + m * 16 + kq * 4;
#pragma unroll
    for (int r = 0; r < 4; ++r) {
      int grow = row0 + lr2 + r;
      const float* rptr = nullptr; int so = 0;
      if (EPI == 1) { so = srcoff[grow]; rptr = (grow < XTOK) ? resx : resy; }
#pragma unroll
      for (int n = 0; n < 4; ++n) {
        int gcol = nbase + wc * 64 + n * 16 + ln15;
        float v = acc[m][n][r] + bs[n];
        if (EPI == 1) v += rptr[(size_t)so + gcol];
        if (EPI == 2) v = gelu_fast(v);
        if (EPI == 3) v += (float)toksr[(size_t)grow * DIMC + gcol];
        acc[m][n][r] = v;
      }
    }
  }

  if (EPI != 3) {
    // bf16 full-tile stage [128][136] -> 256B-contiguous row writes
#pragma unroll
    for (int m = 0; m < 4; ++m)
#pragma unroll
      for (int r = 0; r < 4; ++r)
#pragma unroll
        for (int n = 0; n < 4; ++n)
          smem[(wr * 64 + m * 16 + kq * 4 + r) * 136 + wc * 64 + n * 16 + ln15] = (__bf16)acc[m][n][r];
    __syncthreads();
    __bf16* ob = (EPI == 4 && hi) ? outb2 : outb;
    int ldn = (EPI == 2) ? N : 512;
    int gc0 = (EPI == 2) ? n0 : nbase;
#pragma unroll
    for (int it = 0; it < 8; ++it) {
      int cid = it * 256 + tid;                    // 2048 chunks = 128 rows x 16
      int row = cid >> 4, c = cid & 15;
      i4_t v = *(const i4_t*)&smem[row * 136 + c * 8];
      *(i4_t*)&ob[(size_t)(m0 + row) * ldn + gc0 + c * 8] = v;
    }
  } else {
    // fp32 stage in two 64-col halves [128][68] -> permuted-row d_out writes
    float* stf = (float*)smem;
#pragma unroll
    for (int h = 0; h < 2; ++h) {
      __syncthreads();
      if (wc == h) {
#pragma unroll
        for (int m = 0; m < 4; ++m)
#pragma unroll
          for (int r = 0; r < 4; ++r)
#pragma unroll
            for (int n = 0; n < 4; ++n)
              stf[(wr * 64 + m * 16 + kq * 4 + r) * 68 + n * 16 + ln15] = acc[m][n][r];
      }
      __syncthreads();
#pragma unroll
      for (int it = 0; it < 8; ++it) {
        int cid = it * 256 + tid;
        int row = cid >> 4, c = cid & 15;
        f4_t v = *(const f4_t*)&stf[row * 68 + c * 4];
        int oo = outoff[row0 + m0 + row];
        *(f4_t*)&dout[(size_t)oo + n0 + h * 64 + c * 4] = v;
      }
    }
  }
}

// ---------------- windowed attention v5 (R12 verbatim): swapped-QK, K in LDS ----------------
__global__ __launch_bounds__(512, 4)
void attn_kernel(const __bf16* __restrict__ Qb, const __bf16* __restrict__ Kb,
                 const __bf16* __restrict__ Vb, __bf16* __restrict__ AOb) {
  __shared__ __align__(16) __bf16 smem[32768];       // Kl[16384] + Vt[16384]
  __bf16* Kl = smem;                                  // chunk16 i = s*8 + (c ^ (s&7))
  __bf16* Vt = smem + 16384;                          // el(d,s) = d*256 + (((s>>3)^(d>>3)^(d&7))<<3) + (s&7)
  int tid = threadIdx.x, lane = tid & 63, wid = tid >> 6;
  int l15 = lane & 15, kq = lane >> 4;
  int win = blockIdx.x >> 3, head = blockIdx.x & 7;
  size_t wtok = (size_t)win * 256;
  int hc = head * 64;

#pragma unroll
  for (int it = 0; it < 4; ++it) {
    int i = (wid * 4 + it) * 64 + lane;
    int s = i >> 3, cp = i & 7, c = cp ^ (s & 7);
    gload_lds16(Kb + (wtok + s) * 512 + hc + c * 8, &Kl[(size_t)((wid * 4 + it) * 64) * 8]);
  }
#pragma unroll
  for (int it = 0; it < 4; ++it) {
    int j = tid + it * 512;
    int dc = j & 7, s = j >> 3;
    i4_t v = *(const i4_t*)(Vb + (wtok + s) * 512 + hc + dc * 8);
    const __bf16* ve = (const __bf16*)&v;
#pragma unroll
    for (int jj = 0; jj < 8; ++jj) {
      int d = dc * 8 + jj;
      int sc = (s >> 3) ^ (((d >> 3) ^ d) & 7);
      Vt[d * 256 + (sc << 3) + (s & 7)] = ve[jj];
    }
  }
  __syncthreads();

  const float CLOG2E = 0.18033688011112043f;        // 0.125 * log2(e)
  f4_t oacc[2][4];
  float rinvq[2];
  int sl0 = ((kq & 1) << 5) + l15;
  int sl1 = sl0 + 16;
  bool hiT = (kq & 2) != 0;

#pragma unroll
  for (int qt = 0; qt < 2; ++qt) {
    int qbase = wid * 32 + qt * 16;
    bf8_t qf[2];
#pragma unroll
    for (int k2 = 0; k2 < 2; ++k2)
      qf[k2] = *(const bf8_t*)(Qb + (wtok + qbase + l15) * 512 + hc + k2 * 32 + kq * 8);

    uint2 ps[16];
    float mx = -3.0e38f;
    __builtin_amdgcn_s_setprio(1);
#pragma unroll
    for (int st = 0; st < 16; ++st) {
      f4_t z = {0.f, 0.f, 0.f, 0.f};
      int s = st * 16 + l15;
#pragma unroll
      for (int k2 = 0; k2 < 2; ++k2) {
        int c = (k2 * 4 + kq) ^ (s & 7);
        bf8_t kf = *(const bf8_t*)&Kl[(s * 8 + c) * 8];
        z = __builtin_amdgcn_mfma_f32_16x16x32_bf16(kf, qf[k2], z, 0, 0, 0);
      }
      z *= CLOG2E;
      mx = fmaxf(mx, fmaxf(fmaxf(z[0], z[1]), fmaxf(z[2], z[3])));
      union { __bf16 b[4]; uint2 u; } pk;
#pragma unroll
      for (int r = 0; r < 4; ++r) pk.b[r] = (__bf16)z[r];
      ps[st] = pk.u;
    }
    __builtin_amdgcn_s_setprio(0);
    mx = fmaxf(mx, __shfl_xor(mx, 16, 64));
    mx = fmaxf(mx, __shfl_xor(mx, 32, 64));

    float L = 0.f;
#pragma unroll
    for (int st = 0; st < 16; ++st) {
      uint2 u = ps[st];
      float p0 = __builtin_amdgcn_exp2f(bflo(u.x) - mx);
      float p1 = __builtin_amdgcn_exp2f(bfhi(u.x) - mx);
      float p2 = __builtin_amdgcn_exp2f(bflo(u.y) - mx);
      float p3 = __builtin_amdgcn_exp2f(bfhi(u.y) - mx);
      L += (p0 + p1) + (p2 + p3);
      union { __bf16 b[4]; uint2 u; } pk;
      pk.b[0] = (__bf16)p0; pk.b[1] = (__bf16)p1; pk.b[2] = (__bf16)p2; pk.b[3] = (__bf16)p3;
      ps[st] = pk.u;
    }
    L += __shfl_xor(L, 16, 64);
    L += __shfl_xor(L, 32, 64);
    rinvq[qt] = 1.0f / L;

#pragma unroll
    for (int dn = 0; dn < 4; ++dn) oacc[qt][dn] = f4_t{0.f, 0.f, 0.f, 0.f};
    __builtin_amdgcn_s_setprio(1);
#pragma unroll
    for (int c = 0; c < 8; ++c) {
      uint2 t0 = ps[2 * c], t1 = ps[2 * c + 1];
      int a00x = __shfl((int)t0.x, sl0, 64), a00y = __shfl((int)t0.y, sl0, 64);
      int a01x = __shfl((int)t0.x, sl1, 64), a01y = __shfl((int)t0.y, sl1, 64);
      int a10x = __shfl((int)t1.x, sl0, 64), a10y = __shfl((int)t1.y, sl0, 64);
      int a11x = __shfl((int)t1.x, sl1, 64), a11y = __shfl((int)t1.y, sl1, 64);
      union { int u[4]; bf8_t v; } fr;
      fr.u[0] = hiT ? a10x : a00x;
      fr.u[1] = hiT ? a10y : a00y;
      fr.u[2] = hiT ? a11x : a01x;
      fr.u[3] = hiT ? a11y : a01y;
#pragma unroll
      for (int dn = 0; dn < 4; ++dn) {
        int d = dn * 16 + l15;
        int sc = (4 * c + kq) ^ (((d >> 3) ^ d) & 7);
        bf8_t vf = *(const bf8_t*)&Vt[d * 256 + (sc << 3)];
        oacc[qt][dn] = __builtin_amdgcn_mfma_f32_16x16x32_bf16(fr.v, vf, oacc[qt][dn], 0, 0, 0);
      }
    }
    __builtin_amdgcn_s_setprio(0);
  }

  __syncthreads();
  __bf16* Ko = smem + wid * 2304;                    // [32][72]
#pragma unroll
  for (int qt = 0; qt < 2; ++qt)
#pragma unroll
    for (int dn = 0; dn < 4; ++dn)
#pragma unroll
      for (int r = 0; r < 4; ++r)
        Ko[(qt * 16 + kq * 4 + r) * 72 + dn * 16 + l15] = (__bf16)(oacc[qt][dn][r] * rinvq[qt]);
#pragma unroll
  for (int it = 0; it < 4; ++it) {
    int lr = it * 8 + (lane >> 3), cb = (lane & 7) * 8;
    i4_t v = *(const i4_t*)&Ko[lr * 72 + cb];
    *(i4_t*)&AOb[(wtok + wid * 32 + lr) * 512 + hc + cb] = v;
  }
}

extern "C" void kernel_launch(void* const* d_in, const int* in_sizes, int n_in,
                              void* d_out, int out_size, void* d_ws, size_t ws_size,
                              hipStream_t stream) {
  const float* x  = (const float*)d_in[0];
  const float* y  = (const float*)d_in[1];
  const float* Wq = (const float*)d_in[2];
  const float* bq = (const float*)d_in[3];
  const float* Wk = (const float*)d_in[4];
  const float* bk = (const float*)d_in[5];
  const float* Wv = (const float*)d_in[6];
  const float* bv = (const float*)d_in[7];
  const float* Wo = (const float*)d_in[8];
  const float* bo = (const float*)d_in[9];
  const float* W1 = (const float*)d_in[10];
  const float* b1 = (const float*)d_in[11];
  const float* W2 = (const float*)d_in[12];
  const float* b2 = (const float*)d_in[13];

  char* ws = (char*)d_ws;
  size_t off = 0;
  auto carve = [&](size_t bytes) -> void* {
    void* p = ws + off;
    off += (bytes + 255) & ~(size_t)255;
    return p;
  };
  __bf16* WqvT = (__bf16*)carve((size_t)1024 * 512 * 2);  // [Wq^T; Wv^T]
  __bf16* WkT  = (__bf16*)carve((size_t)512 * 512 * 2);
  __bf16* WoT  = (__bf16*)carve((size_t)512 * 512 * 2);
  __bf16* W1T  = (__bf16*)carve((size_t)2048 * 512 * 2);
  __bf16* W2T  = (__bf16*)carve((size_t)512 * 2048 * 2);
  int* srcoff = (int*)carve((size_t)NTOK * 4);
  int* outoff = (int*)carve((size_t)NTOK * 4);
  __bf16* Asrc = (__bf16*)carve((size_t)NTOK * 512 * 2);
  __bf16* Aoth = (__bf16*)carve((size_t)NTOK * 512 * 2);
  __bf16* Qb   = (__bf16*)carve((size_t)NTOK * 512 * 2);
  __bf16* Kb   = (__bf16*)carve((size_t)NTOK * 512 * 2);
  __bf16* Vb   = (__bf16*)carve((size_t)NTOK * 512 * 2);
  int nc = 1;
  while (nc < 4 && off + (size_t)(NTOK / nc) * 2048 * 2 > ws_size) nc *= 2;
  int rows = NTOK / nc;
  __bf16* Hb = (__bf16*)carve((size_t)rows * 2048 * 2);
  // aliases (lifetimes: producer of alias runs after last reader of original)
  __bf16* AOb   = Asrc;              // attention out  (Asrc dead after QV-GEMM)
  __bf16* toksb = Aoth;              // tokens bf16    (Aoth dead after K-GEMM)
  float*  dout  = (float*)d_out;

  transpose_all<<<3072, 256, 0, stream>>>(Wq, Wv, Wk, Wo, W1, W2, WqvT, WkT, WoT, W1T, W2T);

  pack_tokens<<<NTOK, 256, 0, stream>>>(x, y, Asrc, Aoth, srcoff, outoff);

  gemm_bt<4><<<NTOK / 128 * 8, 256, 0, stream>>>(Asrc, WqvT, bq, bv, 512, 8, 0, Qb, Vb, nullptr, nullptr, nullptr, nullptr, nullptr, nullptr);
  gemm_bt<0><<<NTOK / 128 * 4, 256, 0, stream>>>(Aoth, WkT, bk, nullptr, 512, 4, 0, Kb, nullptr, nullptr, nullptr, nullptr, nullptr, nullptr, nullptr);

  attn_kernel<<<160 * 8, 512, 0, stream>>>(Qb, Kb, Vb, AOb);

  gemm_bt<1><<<NTOK / 128 * 4, 256, 0, stream>>>(AOb, WoT, bo, nullptr, 512, 4, 0, toksb, nullptr, x, y, srcoff, nullptr, nullptr, nullptr);

  for (int c = 0; c < nc; ++c) {
    int r0 = c * rows;
    gemm_bt<2><<<rows / 128 * 16, 256, 0, stream>>>(toksb + (size_t)r0 * 512, W1T, b1, nullptr, 512, 16, r0, Hb, nullptr, nullptr, nullptr, nullptr, nullptr, nullptr, nullptr);
    gemm_bt<3><<<rows / 128 * 4, 256, 0, stream>>>(Hb, W2T, b2, nullptr, 2048, 4, r0, nullptr, nullptr, nullptr, nullptr, nullptr, outoff, toksb, dout);
  }
}

// Round 15
// 546.447 us; speedup vs baseline: 2.8327x; 1.0484x over previous
//
#include <hip/hip_runtime.h>
#include <hip/hip_bf16.h>
#include <math.h>

typedef __attribute__((ext_vector_type(8))) __bf16 bf8_t;
typedef __attribute__((ext_vector_type(4))) float f4_t;
typedef __attribute__((ext_vector_type(4))) int   i4_t;

#define XTOK 32768
#define NTOK 40960
#define DIMC 512

__device__ __forceinline__ void gload_lds16(const __bf16* g, __bf16* l) {
  __builtin_amdgcn_global_load_lds((const __attribute__((address_space(1))) void*)g,
                                   (__attribute__((address_space(3))) void*)l, 16, 0, 0);
}
__device__ __forceinline__ float bflo(unsigned u) { union { unsigned x; float f; } c; c.x = u << 16; return c.f; }
__device__ __forceinline__ float bfhi(unsigned u) { union { unsigned x; float f; } c; c.x = u & 0xffff0000u; return c.f; }

// exact-enough gelu: erf via Abramowitz-Stegun 7.1.26 (|eps|<1.5e-7, below bf16 ulp)
__device__ __forceinline__ float gelu_fast(float v) {
  float u = v * 0.70710678118654752f;
  float a = fabsf(u);
  float t = 1.0f / (1.0f + 0.3275911f * a);
  float e = __builtin_amdgcn_exp2f(-a * a * 1.4426950408889634f);
  float poly = t * (0.254829592f + t * (-0.284496736f + t * (1.421413741f +
               t * (-1.453152027f + t * 1.061405429f))));
  float erfa = 1.0f - poly * e;
  float erfu = (u < 0.0f) ? -erfa : erfa;
  return 0.5f * v * (1.0f + erfu);
}

// ---------------- merged weight transpose + cast: 6 matrices, one launch ----------------
__global__ void transpose_all(const float* __restrict__ Wq, const float* __restrict__ Wv,
                              const float* __restrict__ Wk, const float* __restrict__ Wo,
                              const float* __restrict__ W1, const float* __restrict__ W2,
                              __bf16* __restrict__ WqvT, __bf16* __restrict__ WkT,
                              __bf16* __restrict__ WoT, __bf16* __restrict__ W1T,
                              __bf16* __restrict__ W2T) {
  __shared__ float t[32][33];
  int b = blockIdx.x;
  const float* W; __bf16* WT; int K, N, tb;
  if (b < 256)       { W = Wq; WT = WqvT;                       K = 512;  N = 512;  tb = b; }
  else if (b < 512)  { W = Wv; WT = WqvT + (size_t)512 * 512;   K = 512;  N = 512;  tb = b - 256; }
  else if (b < 768)  { W = Wk; WT = WkT;                        K = 512;  N = 512;  tb = b - 512; }
  else if (b < 1024) { W = Wo; WT = WoT;                        K = 512;  N = 512;  tb = b - 768; }
  else if (b < 2048) { W = W1; WT = W1T;                        K = 512;  N = 2048; tb = b - 1024; }
  else               { W = W2; WT = W2T;                        K = 2048; N = 512;  tb = b - 2048; }
  int ntn = N >> 5;
  int bk = (tb / ntn) * 32, bn = (tb - (tb / ntn) * ntn) * 32;
  int tx = threadIdx.x & 31, ty = threadIdx.x >> 5;   // 32 x 8
#pragma unroll
  for (int i = 0; i < 4; ++i)
    t[ty + i * 8][tx] = W[(size_t)(bk + ty + i * 8) * N + bn + tx];
  __syncthreads();
#pragma unroll
  for (int i = 0; i < 4; ++i)
    WT[(size_t)(bn + ty + i * 8) * K + bk + tx] = (__bf16)t[tx][ty + i * 8];
}

// ---------------- token pack: window-order gather + resize, fp32 -> bf16 ----------------
__global__ void pack_tokens(const float* __restrict__ x, const float* __restrict__ y,
                            __bf16* __restrict__ Asrc, __bf16* __restrict__ Aoth,
                            int* __restrict__ srcoff, int* __restrict__ outoff) {
  int g = blockIdx.x;           // window-ordered token row, 0..40959
  int t = threadIdx.x;          // 256 threads, 2 channels each
  int b, h, w; int soff, ooff; bool isx = (g < XTOK);
  if (isx) {
    b = g >> 12;
    int w5 = g & 4095;
    int widx = w5 >> 8, tt = w5 & 255;
    int wh = widx >> 2, ww = widx & 3;
    h = wh * 16 + (tt >> 4); w = ww * 16 + (tt & 15);
    int n = h * 64 + w;
    soff = (b * 4096 + n) * 512;
    ooff = (b * 5120 + n) * 512;
  } else {
    int gy = g - XTOK;
    b = gy >> 10;
    int w5 = gy & 1023;
    int widx = w5 >> 8, tt = w5 & 255;
    int wh = widx >> 1, ww = widx & 1;
    h = wh * 16 + (tt >> 4); w = ww * 16 + (tt & 15);
    int n = h * 32 + w;
    soff = (b * 1024 + n) * 512;
    ooff = (b * 5120 + 4096 + n) * 512;
  }
  if (t == 0) { srcoff[g] = soff; outoff[g] = ooff; }
  const float* sp = (isx ? x : y) + (size_t)soff + t * 2;
  float2 sv = *(const float2*)sp;
  size_t gb = (size_t)g * 512 + t * 2;
  Asrc[gb]     = (__bf16)sv.x;
  Asrc[gb + 1] = (__bf16)sv.y;

  float o0, o1;
  if (isx) {
    // bilinear upsample 32x32 -> 64x64, half-pixel centers, edge clamp
    int h0, h1, w0i, w1i; float fh0, fh1, fw0, fw1;
    if (h & 1) { h0 = h >> 1; h1 = (h0 + 1 < 31) ? h0 + 1 : 31; fh0 = 0.75f; fh1 = 0.25f; }
    else       { h1 = h >> 1; h0 = (h1 - 1 > 0) ? h1 - 1 : 0;   fh0 = 0.25f; fh1 = 0.75f; }
    if (w & 1) { w0i = w >> 1; w1i = (w0i + 1 < 31) ? w0i + 1 : 31; fw0 = 0.75f; fw1 = 0.25f; }
    else       { w1i = w >> 1; w0i = (w1i - 1 > 0) ? w1i - 1 : 0;   fw0 = 0.25f; fw1 = 0.75f; }
    const float* yb = y + (size_t)b * 1024 * 512 + t * 2;
    float2 v00 = *(const float2*)(yb + (h0 * 32 + w0i) * 512);
    float2 v01 = *(const float2*)(yb + (h0 * 32 + w1i) * 512);
    float2 v10 = *(const float2*)(yb + (h1 * 32 + w0i) * 512);
    float2 v11 = *(const float2*)(yb + (h1 * 32 + w1i) * 512);
    o0 = fh0 * (fw0 * v00.x + fw1 * v01.x) + fh1 * (fw0 * v10.x + fw1 * v11.x);
    o1 = fh0 * (fw0 * v00.y + fw1 * v01.y) + fh1 * (fw0 * v10.y + fw1 * v11.y);
  } else {
    // bilinear downsample 64x64 -> 32x32 == 2x2 average pool
    const float* xb = x + (size_t)b * 4096 * 512 + t * 2;
    float2 v00 = *(const float2*)(xb + ((2 * h) * 64 + 2 * w) * 512);
    float2 v01 = *(const float2*)(xb + ((2 * h) * 64 + 2 * w + 1) * 512);
    float2 v10 = *(const float2*)(xb + ((2 * h + 1) * 64 + 2 * w) * 512);
    float2 v11 = *(const float2*)(xb + ((2 * h + 1) * 64 + 2 * w + 1) * 512);
    o0 = 0.25f * (v00.x + v01.x + v10.x + v11.x);
    o1 = 0.25f * (v00.y + v01.y + v10.y + v11.y);
  }
  Aoth[gb]     = (__bf16)o0;
  Aoth[gb + 1] = (__bf16)o1;
}

// ---------------- GEMM v8b: 128^2 tile, BK=32, 2-slot dbuf, 1 barrier/K-step ----------------
// EPI 0: out bf16 = acc + bias                     (K-proj)
// EPI 1: out bf16 = acc + bias + residual(fp32 src gather)   (Wo -> toksb)
// EPI 2: out bf16 = gelu_fast(acc + bias)          (MLP1)
// EPI 3: fp32 dout at permuted offset = acc + bias + (float)toksb   (MLP2)
// EPI 4: fused QV: n0<512 -> outb (Q, bias), else outb2 (V, bias2)
template<int EPI>
__global__ __launch_bounds__(256, 2)
void gemm_bt(const __bf16* __restrict__ A, const __bf16* __restrict__ BT,
             const float* __restrict__ bias, const float* __restrict__ bias2,
             int K, int nbn, int row0,
             __bf16* __restrict__ outb, __bf16* __restrict__ outb2,
             const float* __restrict__ resx, const float* __restrict__ resy,
             const int* __restrict__ srcoff, const int* __restrict__ outoff,
             const __bf16* __restrict__ toksr, float* __restrict__ dout) {
  const int N = nbn * 128;
  __shared__ __align__(16) __bf16 smem[17408];     // 34816B: 2 slots x 8192 el; epilogue reuse
  // bijective XCD swizzle (m204): contiguous m-major chunk per XCD
  int nwg = gridDim.x;
  int qq = nwg >> 3, rr = nwg & 7;
  int xcd = blockIdx.x & 7, base = blockIdx.x >> 3;
  int wg = (xcd < rr ? xcd * (qq + 1) : rr * (qq + 1) + (xcd - rr) * qq) + base;
  int bm = wg / nbn, bn = wg - bm * nbn;
  int m0 = bm * 128, n0 = bn * 128;

  int tid = threadIdx.x, lane = tid & 63, wid = tid >> 6;
  int wr = wid >> 1, wc = wid & 1;
  int ln15 = lane & 15, kq = lane >> 4;

  f4_t acc[4][4];
#pragma unroll
  for (int m = 0; m < 4; ++m)
#pragma unroll
    for (int n = 0; n < 4; ++n) acc[m][n] = f4_t{0.f, 0.f, 0.f, 0.f};

  // stage K-tile kt into slot. 4 gload_lds16/thread (2 A + 2 B).
  // LDS linear; global source chunk pre-swizzled: chunk = (c&3) ^ (row&3) ^ ((row>>2)&3).
  auto stage = [&](int slot, int kt) {
    int k0 = kt << 5;
    __bf16* dstA = &smem[slot * 8192];
#pragma unroll
    for (int j = 0; j < 2; ++j) {
      int ci = (wid * 2 + j) * 64 + lane;          // chunk index 0..511
      int row = ci >> 2;
      int c = (ci & 3) ^ (row & 3) ^ ((row >> 2) & 3);
      gload_lds16(A  + (size_t)(m0 + row) * K + k0 + c * 8, dstA + (wid * 2 + j) * 512);
      gload_lds16(BT + (size_t)(n0 + row) * K + k0 + c * 8, dstA + 4096 + (wid * 2 + j) * 512);
    }
  };

  int nt = K >> 5;
  stage(0, 0);
  __syncthreads();
  for (int t = 0; t < nt; ++t) {
    int s = t & 1;
    if (t + 1 < nt) stage(s ^ 1, t + 1);           // overlaps with reads+MFMA of tile t
    const __bf16* At = &smem[s * 8192];
    const __bf16* Bt = At + 4096;
    bf8_t av[4], bv[4];
#pragma unroll
    for (int m = 0; m < 4; ++m) {
      int row = wr * 64 + m * 16 + ln15;
      av[m] = *(const bf8_t*)&At[row * 32 + ((kq ^ (row & 3) ^ ((row >> 2) & 3)) << 3)];
    }
#pragma unroll
    for (int n = 0; n < 4; ++n) {
      int row = wc * 64 + n * 16 + ln15;
      bv[n] = *(const bf8_t*)&Bt[row * 32 + ((kq ^ (row & 3) ^ ((row >> 2) & 3)) << 3)];
    }
    __builtin_amdgcn_s_setprio(1);
#pragma unroll
    for (int m = 0; m < 4; ++m)
#pragma unroll
      for (int n = 0; n < 4; ++n)
        acc[m][n] = __builtin_amdgcn_mfma_f32_16x16x32_bf16(av[m], bv[n], acc[m][n], 0, 0, 0);
    __builtin_amdgcn_s_setprio(0);
    __syncthreads();   // drains stage(t+1) writes + reads of slot s
  }

  bool hi = (EPI == 4) && (n0 >= 512);
  const float* bptr = hi ? bias2 : bias;
  int nbase = hi ? n0 - 512 : n0;
  float bs[4];
#pragma unroll
  for (int n = 0; n < 4; ++n) bs[n] = bptr[nbase + wc * 64 + n * 16 + ln15];

  // ---- transform acc in place ----
#pragma unroll
  for (int m = 0; m < 4; ++m) {
    int lr2 = m0 + wr * 64 + m * 16 + kq * 4;
#pragma unroll
    for (int r = 0; r < 4; ++r) {
      int grow = row0 + lr2 + r;
      const float* rptr = nullptr; int so = 0;
      if (EPI == 1) { so = srcoff[grow]; rptr = (grow < XTOK) ? resx : resy; }
#pragma unroll
      for (int n = 0; n < 4; ++n) {
        int gcol = nbase + wc * 64 + n * 16 + ln15;
        float v = acc[m][n][r] + bs[n];
        if (EPI == 1) v += rptr[(size_t)so + gcol];
        if (EPI == 2) v = gelu_fast(v);
        if (EPI == 3) v += (float)toksr[(size_t)grow * DIMC + gcol];
        acc[m][n][r] = v;
      }
    }
  }

  if (EPI != 3) {
    // bf16 full-tile stage [128][136] -> 256B-contiguous row writes
#pragma unroll
    for (int m = 0; m < 4; ++m)
#pragma unroll
      for (int r = 0; r < 4; ++r)
#pragma unroll
        for (int n = 0; n < 4; ++n)
          smem[(wr * 64 + m * 16 + kq * 4 + r) * 136 + wc * 64 + n * 16 + ln15] = (__bf16)acc[m][n][r];
    __syncthreads();
    __bf16* ob = (EPI == 4 && hi) ? outb2 : outb;
    int ldn = (EPI == 2) ? N : 512;
    int gc0 = (EPI == 2) ? n0 : nbase;
#pragma unroll
    for (int it = 0; it < 8; ++it) {
      int cid = it * 256 + tid;                    // 2048 chunks = 128 rows x 16
      int row = cid >> 4, c = cid & 15;
      i4_t v = *(const i4_t*)&smem[row * 136 + c * 8];
      *(i4_t*)&ob[(size_t)(m0 + row) * ldn + gc0 + c * 8] = v;
    }
  } else {
    // fp32 stage in two 64-col halves [128][68] -> permuted-row d_out writes
    float* stf = (float*)smem;
#pragma unroll
    for (int h = 0; h < 2; ++h) {
      __syncthreads();
      if (wc == h) {
#pragma unroll
        for (int m = 0; m < 4; ++m)
#pragma unroll
          for (int r = 0; r < 4; ++r)
#pragma unroll
            for (int n = 0; n < 4; ++n)
              stf[(wr * 64 + m * 16 + kq * 4 + r) * 68 + n * 16 + ln15] = acc[m][n][r];
      }
      __syncthreads();
#pragma unroll
      for (int it = 0; it < 8; ++it) {
        int cid = it * 256 + tid;
        int row = cid >> 4, c = cid & 15;
        f4_t v = *(const f4_t*)&stf[row * 68 + c * 4];
        int oo = outoff[row0 + m0 + row];
        *(f4_t*)&dout[(size_t)oo + n0 + h * 64 + c * 4] = v;
      }
    }
  }
}

// ---------------- windowed attention v7: swapped-QK, K in LDS, NO register spill ------------
// launch_bounds(512,2): VGPR cap 128 fits the ~110 live set (cap 64 at (512,4) caused ~40
// regs of scratch spill = 3x write amplification). LDS 64KB still sets residency (2 blk/CU).
__global__ __launch_bounds__(512, 2)
void attn_kernel(const __bf16* __restrict__ Qb, const __bf16* __restrict__ Kb,
                 const __bf16* __restrict__ Vb, __bf16* __restrict__ AOb) {
  __shared__ __align__(16) __bf16 smem[32768];       // Kl[16384] + Vt[16384]
  __bf16* Kl = smem;                                  // chunk16 i = s*8 + (c ^ (s&7))
  __bf16* Vt = smem + 16384;                          // el(d,s) = d*256 + (((s>>3)^(d>>3)^(d&7))<<3) + (s&7)
  int tid = threadIdx.x, lane = tid & 63, wid = tid >> 6;
  int l15 = lane & 15, kq = lane >> 4;
  int win = blockIdx.x >> 3, head = blockIdx.x & 7;
  size_t wtok = (size_t)win * 256;
  int hc = head * 64;

#pragma unroll
  for (int it = 0; it < 4; ++it) {
    int i = (wid * 4 + it) * 64 + lane;
    int s = i >> 3, cp = i & 7, c = cp ^ (s & 7);
    gload_lds16(Kb + (wtok + s) * 512 + hc + c * 8, &Kl[(size_t)((wid * 4 + it) * 64) * 8]);
  }
#pragma unroll
  for (int it = 0; it < 4; ++it) {
    int j = tid + it * 512;
    int dc = j & 7, s = j >> 3;
    i4_t v = *(const i4_t*)(Vb + (wtok + s) * 512 + hc + dc * 8);
    const __bf16* ve = (const __bf16*)&v;
#pragma unroll
    for (int jj = 0; jj < 8; ++jj) {
      int d = dc * 8 + jj;
      int sc = (s >> 3) ^ (((d >> 3) ^ d) & 7);
      Vt[d * 256 + (sc << 3) + (s & 7)] = ve[jj];
    }
  }
  __syncthreads();

  const float CLOG2E = 0.18033688011112043f;        // 0.125 * log2(e)
  f4_t oacc[2][4];
  float rinvq[2];
  int sl0 = ((kq & 1) << 5) + l15;
  int sl1 = sl0 + 16;
  bool hiT = (kq & 2) != 0;

#pragma unroll
  for (int qt = 0; qt < 2; ++qt) {
    int qbase = wid * 32 + qt * 16;
    bf8_t qf[2];
#pragma unroll
    for (int k2 = 0; k2 < 2; ++k2)
      qf[k2] = *(const bf8_t*)(Qb + (wtok + qbase + l15) * 512 + hc + k2 * 32 + kq * 8);

    uint2 ps[16];
    float mx = -3.0e38f;
    __builtin_amdgcn_s_setprio(1);
#pragma unroll
    for (int st = 0; st < 16; ++st) {
      f4_t z = {0.f, 0.f, 0.f, 0.f};
      int s = st * 16 + l15;
#pragma unroll
      for (int k2 = 0; k2 < 2; ++k2) {
        int c = (k2 * 4 + kq) ^ (s & 7);
        bf8_t kf = *(const bf8_t*)&Kl[(s * 8 + c) * 8];
        z = __builtin_amdgcn_mfma_f32_16x16x32_bf16(kf, qf[k2], z, 0, 0, 0);
      }
      z *= CLOG2E;
      mx = fmaxf(mx, fmaxf(fmaxf(z[0], z[1]), fmaxf(z[2], z[3])));
      union { __bf16 b[4]; uint2 u; } pk;
#pragma unroll
      for (int r = 0; r < 4; ++r) pk.b[r] = (__bf16)z[r];
      ps[st] = pk.u;
    }
    __builtin_amdgcn_s_setprio(0);
    mx = fmaxf(mx, __shfl_xor(mx, 16, 64));
    mx = fmaxf(mx, __shfl_xor(mx, 32, 64));

    float L = 0.f;
#pragma unroll
    for (int st = 0; st < 16; ++st) {
      uint2 u = ps[st];
      float p0 = __builtin_amdgcn_exp2f(bflo(u.x) - mx);
      float p1 = __builtin_amdgcn_exp2f(bfhi(u.x) - mx);
      float p2 = __builtin_amdgcn_exp2f(bflo(u.y) - mx);
      float p3 = __builtin_amdgcn_exp2f(bfhi(u.y) - mx);
      L += (p0 + p1) + (p2 + p3);
      union { __bf16 b[4]; uint2 u; } pk;
      pk.b[0] = (__bf16)p0; pk.b[1] = (__bf16)p1; pk.b[2] = (__bf16)p2; pk.b[3] = (__bf16)p3;
      ps[st] = pk.u;
    }
    L += __shfl_xor(L, 16, 64);
    L += __shfl_xor(L, 32, 64);
    rinvq[qt] = 1.0f / L;

#pragma unroll
    for (int dn = 0; dn < 4; ++dn) oacc[qt][dn] = f4_t{0.f, 0.f, 0.f, 0.f};
    __builtin_amdgcn_s_setprio(1);
#pragma unroll
    for (int c = 0; c < 8; ++c) {
      uint2 t0 = ps[2 * c], t1 = ps[2 * c + 1];
      int a00x = __shfl((int)t0.x, sl0, 64), a00y = __shfl((int)t0.y, sl0, 64);
      int a01x = __shfl((int)t0.x, sl1, 64), a01y = __shfl((int)t0.y, sl1, 64);
      int a10x = __shfl((int)t1.x, sl0, 64), a10y = __shfl((int)t1.y, sl0, 64);
      int a11x = __shfl((int)t1.x, sl1, 64), a11y = __shfl((int)t1.y, sl1, 64);
      union { int u[4]; bf8_t v; } fr;
      fr.u[0] = hiT ? a10x : a00x;
      fr.u[1] = hiT ? a10y : a00y;
      fr.u[2] = hiT ? a11x : a01x;
      fr.u[3] = hiT ? a11y : a01y;
#pragma unroll
      for (int dn = 0; dn < 4; ++dn) {
        int d = dn * 16 + l15;
        int sc = (4 * c + kq) ^ (((d >> 3) ^ d) & 7);
        bf8_t vf = *(const bf8_t*)&Vt[d * 256 + (sc << 3)];
        oacc[qt][dn] = __builtin_amdgcn_mfma_f32_16x16x32_bf16(fr.v, vf, oacc[qt][dn], 0, 0, 0);
      }
    }
    __builtin_amdgcn_s_setprio(0);
  }

  __syncthreads();
  __bf16* Ko = smem + wid * 2304;                    // [32][72]
#pragma unroll
  for (int qt = 0; qt < 2; ++qt)
#pragma unroll
    for (int dn = 0; dn < 4; ++dn)
#pragma unroll
      for (int r = 0; r < 4; ++r)
        Ko[(qt * 16 + kq * 4 + r) * 72 + dn * 16 + l15] = (__bf16)(oacc[qt][dn][r] * rinvq[qt]);
#pragma unroll
  for (int it = 0; it < 4; ++it) {
    int lr = it * 8 + (lane >> 3), cb = (lane & 7) * 8;
    i4_t v = *(const i4_t*)&Ko[lr * 72 + cb];
    *(i4_t*)&AOb[(wtok + wid * 32 + lr) * 512 + hc + cb] = v;
  }
}

extern "C" void kernel_launch(void* const* d_in, const int* in_sizes, int n_in,
                              void* d_out, int out_size, void* d_ws, size_t ws_size,
                              hipStream_t stream) {
  const float* x  = (const float*)d_in[0];
  const float* y  = (const float*)d_in[1];
  const float* Wq = (const float*)d_in[2];
  const float* bq = (const float*)d_in[3];
  const float* Wk = (const float*)d_in[4];
  const float* bk = (const float*)d_in[5];
  const float* Wv = (const float*)d_in[6];
  const float* bv = (const float*)d_in[7];
  const float* Wo = (const float*)d_in[8];
  const float* bo = (const float*)d_in[9];
  const float* W1 = (const float*)d_in[10];
  const float* b1 = (const float*)d_in[11];
  const float* W2 = (const float*)d_in[12];
  const float* b2 = (const float*)d_in[13];

  char* ws = (char*)d_ws;
  size_t off = 0;
  auto carve = [&](size_t bytes) -> void* {
    void* p = ws + off;
    off += (bytes + 255) & ~(size_t)255;
    return p;
  };
  __bf16* WqvT = (__bf16*)carve((size_t)1024 * 512 * 2);  // [Wq^T; Wv^T]
  __bf16* WkT  = (__bf16*)carve((size_t)512 * 512 * 2);
  __bf16* WoT  = (__bf16*)carve((size_t)512 * 512 * 2);
  __bf16* W1T  = (__bf16*)carve((size_t)2048 * 512 * 2);
  __bf16* W2T  = (__bf16*)carve((size_t)512 * 2048 * 2);
  int* srcoff = (int*)carve((size_t)NTOK * 4);
  int* outoff = (int*)carve((size_t)NTOK * 4);
  __bf16* Asrc = (__bf16*)carve((size_t)NTOK * 512 * 2);
  __bf16* Aoth = (__bf16*)carve((size_t)NTOK * 512 * 2);
  __bf16* Qb   = (__bf16*)carve((size_t)NTOK * 512 * 2);
  __bf16* Kb   = (__bf16*)carve((size_t)NTOK * 512 * 2);
  __bf16* Vb   = (__bf16*)carve((size_t)NTOK * 512 * 2);
  int nc = 1;
  while (nc < 4 && off + (size_t)(NTOK / nc) * 2048 * 2 > ws_size) nc *= 2;
  int rows = NTOK / nc;
  __bf16* Hb = (__bf16*)carve((size_t)rows * 2048 * 2);
  // aliases (lifetimes: producer of alias runs after last reader of original)
  __bf16* AOb   = Asrc;              // attention out  (Asrc dead after QV-GEMM)
  __bf16* toksb = Aoth;              // tokens bf16    (Aoth dead after K-GEMM)
  float*  dout  = (float*)d_out;

  transpose_all<<<3072, 256, 0, stream>>>(Wq, Wv, Wk, Wo, W1, W2, WqvT, WkT, WoT, W1T, W2T);

  pack_tokens<<<NTOK, 256, 0, stream>>>(x, y, Asrc, Aoth, srcoff, outoff);

  gemm_bt<4><<<NTOK / 128 * 8, 256, 0, stream>>>(Asrc, WqvT, bq, bv, 512, 8, 0, Qb, Vb, nullptr, nullptr, nullptr, nullptr, nullptr, nullptr);
  gemm_bt<0><<<NTOK / 128 * 4, 256, 0, stream>>>(Aoth, WkT, bk, nullptr, 512, 4, 0, Kb, nullptr, nullptr, nullptr, nullptr, nullptr, nullptr, nullptr);

  attn_kernel<<<160 * 8, 512, 0, stream>>>(Qb, Kb, Vb, AOb);

  gemm_bt<1><<<NTOK / 128 * 4, 256, 0, stream>>>(AOb, WoT, bo, nullptr, 512, 4, 0, toksb, nullptr, x, y, srcoff, nullptr, nullptr, nullptr);

  for (int c = 0; c < nc; ++c) {
    int r0 = c * rows;
    gemm_bt<2><<<rows / 128 * 16, 256, 0, stream>>>(toksb + (size_t)r0 * 512, W1T, b1, nullptr, 512, 16, r0, Hb, nullptr, nullptr, nullptr, nullptr, nullptr, nullptr, nullptr);
    gemm_bt<3><<<rows / 128 * 4, 256, 0, stream>>>(Hb, W2T, b2, nullptr, 2048, 4, r0, nullptr, nullptr, nullptr, nullptr, nullptr, outoff, toksb, dout);
  }
}

// Round 16
// 531.504 us; speedup vs baseline: 2.9123x; 1.0281x over previous
//
#include <hip/hip_runtime.h>
#include <hip/hip_bf16.h>
#include <math.h>

typedef __attribute__((ext_vector_type(8))) __bf16 bf8_t;
typedef __attribute__((ext_vector_type(4))) float f4_t;
typedef __attribute__((ext_vector_type(4))) int   i4_t;

#define XTOK 32768
#define NTOK 40960
#define DIMC 512

__device__ __forceinline__ void gload_lds16(const __bf16* g, __bf16* l) {
  __builtin_amdgcn_global_load_lds((const __attribute__((address_space(1))) void*)g,
                                   (__attribute__((address_space(3))) void*)l, 16, 0, 0);
}
__device__ __forceinline__ float bflo(unsigned u) { union { unsigned x; float f; } c; c.x = u << 16; return c.f; }
__device__ __forceinline__ float bfhi(unsigned u) { union { unsigned x; float f; } c; c.x = u & 0xffff0000u; return c.f; }

// exact-enough gelu: erf via Abramowitz-Stegun 7.1.26 (|eps|<1.5e-7, below bf16 ulp)
__device__ __forceinline__ float gelu_fast(float v) {
  float u = v * 0.70710678118654752f;
  float a = fabsf(u);
  float t = __builtin_amdgcn_rcpf(1.0f + 0.3275911f * a);
  float e = __builtin_amdgcn_exp2f(-a * a * 1.4426950408889634f);
  float poly = t * (0.254829592f + t * (-0.284496736f + t * (1.421413741f +
               t * (-1.453152027f + t * 1.061405429f))));
  float erfa = 1.0f - poly * e;
  float erfu = (u < 0.0f) ? -erfa : erfa;
  return 0.5f * v * (1.0f + erfu);
}

// ---------------- merged weight transpose + cast: 6 matrices, one launch ----------------
__global__ void transpose_all(const float* __restrict__ Wq, const float* __restrict__ Wv,
                              const float* __restrict__ Wk, const float* __restrict__ Wo,
                              const float* __restrict__ W1, const float* __restrict__ W2,
                              __bf16* __restrict__ WqvT, __bf16* __restrict__ WkT,
                              __bf16* __restrict__ WoT, __bf16* __restrict__ W1T,
                              __bf16* __restrict__ W2T) {
  __shared__ float t[32][33];
  int b = blockIdx.x;
  const float* W; __bf16* WT; int K, N, tb;
  if (b < 256)       { W = Wq; WT = WqvT;                       K = 512;  N = 512;  tb = b; }
  else if (b < 512)  { W = Wv; WT = WqvT + (size_t)512 * 512;   K = 512;  N = 512;  tb = b - 256; }
  else if (b < 768)  { W = Wk; WT = WkT;                        K = 512;  N = 512;  tb = b - 512; }
  else if (b < 1024) { W = Wo; WT = WoT;                        K = 512;  N = 512;  tb = b - 768; }
  else if (b < 2048) { W = W1; WT = W1T;                        K = 512;  N = 2048; tb = b - 1024; }
  else               { W = W2; WT = W2T;                        K = 2048; N = 512;  tb = b - 2048; }
  int ntn = N >> 5;
  int bk = (tb / ntn) * 32, bn = (tb - (tb / ntn) * ntn) * 32;
  int tx = threadIdx.x & 31, ty = threadIdx.x >> 5;   // 32 x 8
#pragma unroll
  for (int i = 0; i < 4; ++i)
    t[ty + i * 8][tx] = W[(size_t)(bk + ty + i * 8) * N + bn + tx];
  __syncthreads();
#pragma unroll
  for (int i = 0; i < 4; ++i)
    WT[(size_t)(bn + ty + i * 8) * K + bk + tx] = (__bf16)t[tx][ty + i * 8];
}

// ---------------- token pack: window-order gather + resize, fp32 -> bf16 ----------------
__global__ void pack_tokens(const float* __restrict__ x, const float* __restrict__ y,
                            __bf16* __restrict__ Asrc, __bf16* __restrict__ Aoth,
                            int* __restrict__ srcoff, int* __restrict__ outoff) {
  int g = blockIdx.x;           // window-ordered token row, 0..40959
  int t = threadIdx.x;          // 256 threads, 2 channels each
  int b, h, w; int soff, ooff; bool isx = (g < XTOK);
  if (isx) {
    b = g >> 12;
    int w5 = g & 4095;
    int widx = w5 >> 8, tt = w5 & 255;
    int wh = widx >> 2, ww = widx & 3;
    h = wh * 16 + (tt >> 4); w = ww * 16 + (tt & 15);
    int n = h * 64 + w;
    soff = (b * 4096 + n) * 512;
    ooff = (b * 5120 + n) * 512;
  } else {
    int gy = g - XTOK;
    b = gy >> 10;
    int w5 = gy & 1023;
    int widx = w5 >> 8, tt = w5 & 255;
    int wh = widx >> 1, ww = widx & 1;
    h = wh * 16 + (tt >> 4); w = ww * 16 + (tt & 15);
    int n = h * 32 + w;
    soff = (b * 1024 + n) * 512;
    ooff = (b * 5120 + 4096 + n) * 512;
  }
  if (t == 0) { srcoff[g] = soff; outoff[g] = ooff; }
  const float* sp = (isx ? x : y) + (size_t)soff + t * 2;
  float2 sv = *(const float2*)sp;
  size_t gb = (size_t)g * 512 + t * 2;
  Asrc[gb]     = (__bf16)sv.x;
  Asrc[gb + 1] = (__bf16)sv.y;

  float o0, o1;
  if (isx) {
    // bilinear upsample 32x32 -> 64x64, half-pixel centers, edge clamp
    int h0, h1, w0i, w1i; float fh0, fh1, fw0, fw1;
    if (h & 1) { h0 = h >> 1; h1 = (h0 + 1 < 31) ? h0 + 1 : 31; fh0 = 0.75f; fh1 = 0.25f; }
    else       { h1 = h >> 1; h0 = (h1 - 1 > 0) ? h1 - 1 : 0;   fh0 = 0.25f; fh1 = 0.75f; }
    if (w & 1) { w0i = w >> 1; w1i = (w0i + 1 < 31) ? w0i + 1 : 31; fw0 = 0.75f; fw1 = 0.25f; }
    else       { w1i = w >> 1; w0i = (w1i - 1 > 0) ? w1i - 1 : 0;   fw0 = 0.25f; fw1 = 0.75f; }
    const float* yb = y + (size_t)b * 1024 * 512 + t * 2;
    float2 v00 = *(const float2*)(yb + (h0 * 32 + w0i) * 512);
    float2 v01 = *(const float2*)(yb + (h0 * 32 + w1i) * 512);
    float2 v10 = *(const float2*)(yb + (h1 * 32 + w0i) * 512);
    float2 v11 = *(const float2*)(yb + (h1 * 32 + w1i) * 512);
    o0 = fh0 * (fw0 * v00.x + fw1 * v01.x) + fh1 * (fw0 * v10.x + fw1 * v11.x);
    o1 = fh0 * (fw0 * v00.y + fw1 * v01.y) + fh1 * (fw0 * v10.y + fw1 * v11.y);
  } else {
    // bilinear downsample 64x64 -> 32x32 == 2x2 average pool
    const float* xb = x + (size_t)b * 4096 * 512 + t * 2;
    float2 v00 = *(const float2*)(xb + ((2 * h) * 64 + 2 * w) * 512);
    float2 v01 = *(const float2*)(xb + ((2 * h) * 64 + 2 * w + 1) * 512);
    float2 v10 = *(const float2*)(xb + ((2 * h + 1) * 64 + 2 * w) * 512);
    float2 v11 = *(const float2*)(xb + ((2 * h + 1) * 64 + 2 * w + 1) * 512);
    o0 = 0.25f * (v00.x + v01.x + v10.x + v11.x);
    o1 = 0.25f * (v00.y + v01.y + v10.y + v11.y);
  }
  Aoth[gb]     = (__bf16)o0;
  Aoth[gb + 1] = (__bf16)o1;
}

// ---------------- GEMM v9: 128^2 tile, BK=32, 2-slot dbuf, unroll-by-2 (static slots) -------
// K-loop processes 2 tiles/iteration with compile-time slot bases; LDS read offsets hoisted.
// EPI 0: out bf16 = acc + bias                     (K-proj)
// EPI 1: out bf16 = acc + bias + residual(fp32 src gather)   (Wo -> toksb)
// EPI 2: out bf16 = gelu_fast(acc + bias)          (MLP1)
// EPI 3: fp32 dout at permuted offset = acc + bias + (float)toksb   (MLP2)
// EPI 4: fused QV: n0<512 -> outb (Q, bias), else outb2 (V, bias2)
template<int EPI>
__global__ __launch_bounds__(256, 2)
void gemm_bt(const __bf16* __restrict__ A, const __bf16* __restrict__ BT,
             const float* __restrict__ bias, const float* __restrict__ bias2,
             int K, int nbn, int row0,
             __bf16* __restrict__ outb, __bf16* __restrict__ outb2,
             const float* __restrict__ resx, const float* __restrict__ resy,
             const int* __restrict__ srcoff, const int* __restrict__ outoff,
             const __bf16* __restrict__ toksr, float* __restrict__ dout) {
  const int N = nbn * 128;
  __shared__ __align__(16) __bf16 smem[17408];     // 34816B: 2 slots x 8192 el; epilogue reuse
  // bijective XCD swizzle (m204): contiguous m-major chunk per XCD
  int nwg = gridDim.x;
  int qq = nwg >> 3, rr = nwg & 7;
  int xcd = blockIdx.x & 7, base = blockIdx.x >> 3;
  int wg = (xcd < rr ? xcd * (qq + 1) : rr * (qq + 1) + (xcd - rr) * qq) + base;
  int bm = wg / nbn, bn = wg - bm * nbn;
  int m0 = bm * 128, n0 = bn * 128;

  int tid = threadIdx.x, lane = tid & 63, wid = tid >> 6;
  int wr = wid >> 1, wc = wid & 1;
  int ln15 = lane & 15, kq = lane >> 4;

  f4_t acc[4][4];
#pragma unroll
  for (int m = 0; m < 4; ++m)
#pragma unroll
    for (int n = 0; n < 4; ++n) acc[m][n] = f4_t{0.f, 0.f, 0.f, 0.f};

  // hoisted LDS read offsets (element idx within a slot)
  int offA[4], offB[4];
#pragma unroll
  for (int m = 0; m < 4; ++m) {
    int row = wr * 64 + m * 16 + ln15;
    offA[m] = row * 32 + ((kq ^ (row & 3) ^ ((row >> 2) & 3)) << 3);
  }
#pragma unroll
  for (int n = 0; n < 4; ++n) {
    int row = wc * 64 + n * 16 + ln15;
    offB[n] = 4096 + row * 32 + ((kq ^ (row & 3) ^ ((row >> 2) & 3)) << 3);
  }
  // hoisted staging constants: per-thread (row, chunk) for the 2 gload pairs
  int srow[2], scol[2], sdst[2];
#pragma unroll
  for (int j = 0; j < 2; ++j) {
    int ci = (wid * 2 + j) * 64 + lane;
    int row = ci >> 2;
    srow[j] = row;
    scol[j] = ((ci & 3) ^ (row & 3) ^ ((row >> 2) & 3)) * 8;
    sdst[j] = (wid * 2 + j) * 512;
  }

  auto stage = [&](int slotbase, int kt) {
    int k0 = kt << 5;
#pragma unroll
    for (int j = 0; j < 2; ++j) {
      gload_lds16(A  + (size_t)(m0 + srow[j]) * K + k0 + scol[j], &smem[slotbase + sdst[j]]);
      gload_lds16(BT + (size_t)(n0 + srow[j]) * K + k0 + scol[j], &smem[slotbase + 4096 + sdst[j]]);
    }
  };

#define GEMM_HALF(SLOTBASE)                                                       \
  do {                                                                            \
    bf8_t av[4], bv[4];                                                           \
    _Pragma("unroll")                                                             \
    for (int m = 0; m < 4; ++m) av[m] = *(const bf8_t*)&smem[(SLOTBASE) + offA[m]]; \
    _Pragma("unroll")                                                             \
    for (int n = 0; n < 4; ++n) bv[n] = *(const bf8_t*)&smem[(SLOTBASE) + offB[n]]; \
    __builtin_amdgcn_s_setprio(1);                                                \
    _Pragma("unroll")                                                             \
    for (int m = 0; m < 4; ++m) {                                                 \
      _Pragma("unroll")                                                           \
      for (int n = 0; n < 4; ++n)                                                 \
        acc[m][n] = __builtin_amdgcn_mfma_f32_16x16x32_bf16(av[m], bv[n], acc[m][n], 0, 0, 0); \
    }                                                                             \
    __builtin_amdgcn_s_setprio(0);                                                \
  } while (0)

  int nt = K >> 5;                                  // always even (16 or 64)
  stage(0, 0);
  __syncthreads();
  for (int t = 0; t < nt; t += 2) {
    stage(8192, t + 1);                             // t+1 <= nt-1 always
    GEMM_HALF(0);
    __syncthreads();
    if (t + 2 < nt) stage(0, t + 2);
    GEMM_HALF(8192);
    __syncthreads();
  }
#undef GEMM_HALF

  bool hi = (EPI == 4) && (n0 >= 512);
  const float* bptr = hi ? bias2 : bias;
  int nbase = hi ? n0 - 512 : n0;
  float bs[4];
#pragma unroll
  for (int n = 0; n < 4; ++n) bs[n] = bptr[nbase + wc * 64 + n * 16 + ln15];

  // ---- transform acc in place ----
#pragma unroll
  for (int m = 0; m < 4; ++m) {
    int lr2 = m0 + wr * 64 + m * 16 + kq * 4;
#pragma unroll
    for (int r = 0; r < 4; ++r) {
      int grow = row0 + lr2 + r;
      const float* rptr = nullptr; int so = 0;
      if (EPI == 1) { so = srcoff[grow]; rptr = (grow < XTOK) ? resx : resy; }
#pragma unroll
      for (int n = 0; n < 4; ++n) {
        int gcol = nbase + wc * 64 + n * 16 + ln15;
        float v = acc[m][n][r] + bs[n];
        if (EPI == 1) v += rptr[(size_t)so + gcol];
        if (EPI == 2) v = gelu_fast(v);
        if (EPI == 3) v += (float)toksr[(size_t)grow * DIMC + gcol];
        acc[m][n][r] = v;
      }
    }
  }

  if (EPI != 3) {
    // bf16 full-tile stage [128][136] -> 256B-contiguous row writes
#pragma unroll
    for (int m = 0; m < 4; ++m)
#pragma unroll
      for (int r = 0; r < 4; ++r)
#pragma unroll
        for (int n = 0; n < 4; ++n)
          smem[(wr * 64 + m * 16 + kq * 4 + r) * 136 + wc * 64 + n * 16 + ln15] = (__bf16)acc[m][n][r];
    __syncthreads();
    __bf16* ob = (EPI == 4 && hi) ? outb2 : outb;
    int ldn = (EPI == 2) ? N : 512;
    int gc0 = (EPI == 2) ? n0 : nbase;
#pragma unroll
    for (int it = 0; it < 8; ++it) {
      int cid = it * 256 + tid;                    // 2048 chunks = 128 rows x 16
      int row = cid >> 4, c = cid & 15;
      i4_t v = *(const i4_t*)&smem[row * 136 + c * 8];
      *(i4_t*)&ob[(size_t)(m0 + row) * ldn + gc0 + c * 8] = v;
    }
  } else {
    // fp32 stage in two 64-col halves [128][68] -> permuted-row d_out writes
    float* stf = (float*)smem;
#pragma unroll
    for (int h = 0; h < 2; ++h) {
      __syncthreads();
      if (wc == h) {
#pragma unroll
        for (int m = 0; m < 4; ++m)
#pragma unroll
          for (int r = 0; r < 4; ++r)
#pragma unroll
            for (int n = 0; n < 4; ++n)
              stf[(wr * 64 + m * 16 + kq * 4 + r) * 68 + n * 16 + ln15] = acc[m][n][r];
      }
      __syncthreads();
#pragma unroll
      for (int it = 0; it < 8; ++it) {
        int cid = it * 256 + tid;
        int row = cid >> 4, c = cid & 15;
        f4_t v = *(const f4_t*)&stf[row * 68 + c * 4];
        int oo = outoff[row0 + m0 + row];
        *(f4_t*)&dout[(size_t)oo + n0 + h * 64 + c * 4] = v;
      }
    }
  }
}

// ---------------- windowed attention v7: swapped-QK, K in LDS, no spill ----------------
__global__ __launch_bounds__(512, 2)
void attn_kernel(const __bf16* __restrict__ Qb, const __bf16* __restrict__ Kb,
                 const __bf16* __restrict__ Vb, __bf16* __restrict__ AOb) {
  __shared__ __align__(16) __bf16 smem[32768];       // Kl[16384] + Vt[16384]
  __bf16* Kl = smem;                                  // chunk16 i = s*8 + (c ^ (s&7))
  __bf16* Vt = smem + 16384;                          // el(d,s) = d*256 + (((s>>3)^(d>>3)^(d&7))<<3) + (s&7)
  int tid = threadIdx.x, lane = tid & 63, wid = tid >> 6;
  int l15 = lane & 15, kq = lane >> 4;
  int win = blockIdx.x >> 3, head = blockIdx.x & 7;
  size_t wtok = (size_t)win * 256;
  int hc = head * 64;

#pragma unroll
  for (int it = 0; it < 4; ++it) {
    int i = (wid * 4 + it) * 64 + lane;
    int s = i >> 3, cp = i & 7, c = cp ^ (s & 7);
    gload_lds16(Kb + (wtok + s) * 512 + hc + c * 8, &Kl[(size_t)((wid * 4 + it) * 64) * 8]);
  }
#pragma unroll
  for (int it = 0; it < 4; ++it) {
    int j = tid + it * 512;
    int dc = j & 7, s = j >> 3;
    i4_t v = *(const i4_t*)(Vb + (wtok + s) * 512 + hc + dc * 8);
    const __bf16* ve = (const __bf16*)&v;
#pragma unroll
    for (int jj = 0; jj < 8; ++jj) {
      int d = dc * 8 + jj;
      int sc = (s >> 3) ^ (((d >> 3) ^ d) & 7);
      Vt[d * 256 + (sc << 3) + (s & 7)] = ve[jj];
    }
  }
  __syncthreads();

  const float CLOG2E = 0.18033688011112043f;        // 0.125 * log2(e)
  f4_t oacc[2][4];
  float rinvq[2];
  int sl0 = ((kq & 1) << 5) + l15;
  int sl1 = sl0 + 16;
  bool hiT = (kq & 2) != 0;

#pragma unroll
  for (int qt = 0; qt < 2; ++qt) {
    int qbase = wid * 32 + qt * 16;
    bf8_t qf[2];
#pragma unroll
    for (int k2 = 0; k2 < 2; ++k2)
      qf[k2] = *(const bf8_t*)(Qb + (wtok + qbase + l15) * 512 + hc + k2 * 32 + kq * 8);

    uint2 ps[16];
    float mx = -3.0e38f;
    __builtin_amdgcn_s_setprio(1);
#pragma unroll
    for (int st = 0; st < 16; ++st) {
      f4_t z = {0.f, 0.f, 0.f, 0.f};
      int s = st * 16 + l15;
#pragma unroll
      for (int k2 = 0; k2 < 2; ++k2) {
        int c = (k2 * 4 + kq) ^ (s & 7);
        bf8_t kf = *(const bf8_t*)&Kl[(s * 8 + c) * 8];
        z = __builtin_amdgcn_mfma_f32_16x16x32_bf16(kf, qf[k2], z, 0, 0, 0);
      }
      z *= CLOG2E;
      mx = fmaxf(mx, fmaxf(fmaxf(z[0], z[1]), fmaxf(z[2], z[3])));
      union { __bf16 b[4]; uint2 u; } pk;
#pragma unroll
      for (int r = 0; r < 4; ++r) pk.b[r] = (__bf16)z[r];
      ps[st] = pk.u;
    }
    __builtin_amdgcn_s_setprio(0);
    mx = fmaxf(mx, __shfl_xor(mx, 16, 64));
    mx = fmaxf(mx, __shfl_xor(mx, 32, 64));

    float L = 0.f;
#pragma unroll
    for (int st = 0; st < 16; ++st) {
      uint2 u = ps[st];
      float p0 = __builtin_amdgcn_exp2f(bflo(u.x) - mx);
      float p1 = __builtin_amdgcn_exp2f(bfhi(u.x) - mx);
      float p2 = __builtin_amdgcn_exp2f(bflo(u.y) - mx);
      float p3 = __builtin_amdgcn_exp2f(bfhi(u.y) - mx);
      L += (p0 + p1) + (p2 + p3);
      union { __bf16 b[4]; uint2 u; } pk;
      pk.b[0] = (__bf16)p0; pk.b[1] = (__bf16)p1; pk.b[2] = (__bf16)p2; pk.b[3] = (__bf16)p3;
      ps[st] = pk.u;
    }
    L += __shfl_xor(L, 16, 64);
    L += __shfl_xor(L, 32, 64);
    rinvq[qt] = __builtin_amdgcn_rcpf(L);

#pragma unroll
    for (int dn = 0; dn < 4; ++dn) oacc[qt][dn] = f4_t{0.f, 0.f, 0.f, 0.f};
    __builtin_amdgcn_s_setprio(1);
#pragma unroll
    for (int c = 0; c < 8; ++c) {
      uint2 t0 = ps[2 * c], t1 = ps[2 * c + 1];
      int a00x = __shfl((int)t0.x, sl0, 64), a00y = __shfl((int)t0.y, sl0, 64);
      int a01x = __shfl((int)t0.x, sl1, 64), a01y = __shfl((int)t0.y, sl1, 64);
      int a10x = __shfl((int)t1.x, sl0, 64), a10y = __shfl((int)t1.y, sl0, 64);
      int a11x = __shfl((int)t1.x, sl1, 64), a11y = __shfl((int)t1.y, sl1, 64);
      union { int u[4]; bf8_t v; } fr;
      fr.u[0] = hiT ? a10x : a00x;
      fr.u[1] = hiT ? a10y : a00y;
      fr.u[2] = hiT ? a11x : a01x;
      fr.u[3] = hiT ? a11y : a01y;
#pragma unroll
      for (int dn = 0; dn < 4; ++dn) {
        int d = dn * 16 + l15;
        int sc = (4 * c + kq) ^ (((d >> 3) ^ d) & 7);
        bf8_t vf = *(const bf8_t*)&Vt[d * 256 + (sc << 3)];
        oacc[qt][dn] = __builtin_amdgcn_mfma_f32_16x16x32_bf16(fr.v, vf, oacc[qt][dn], 0, 0, 0);
      }
    }
    __builtin_amdgcn_s_setprio(0);
  }

  __syncthreads();
  __bf16* Ko = smem + wid * 2304;                    // [32][72]
#pragma unroll
  for (int qt = 0; qt < 2; ++qt)
#pragma unroll
    for (int dn = 0; dn < 4; ++dn)
#pragma unroll
      for (int r = 0; r < 4; ++r)
        Ko[(qt * 16 + kq * 4 + r) * 72 + dn * 16 + l15] = (__bf16)(oacc[qt][dn][r] * rinvq[qt]);
#pragma unroll
  for (int it = 0; it < 4; ++it) {
    int lr = it * 8 + (lane >> 3), cb = (lane & 7) * 8;
    i4_t v = *(const i4_t*)&Ko[lr * 72 + cb];
    *(i4_t*)&AOb[(wtok + wid * 32 + lr) * 512 + hc + cb] = v;
  }
}

extern "C" void kernel_launch(void* const* d_in, const int* in_sizes, int n_in,
                              void* d_out, int out_size, void* d_ws, size_t ws_size,
                              hipStream_t stream) {
  const float* x  = (const float*)d_in[0];
  const float* y  = (const float*)d_in[1];
  const float* Wq = (const float*)d_in[2];
  const float* bq = (const float*)d_in[3];
  const float* Wk = (const float*)d_in[4];
  const float* bk = (const float*)d_in[5];
  const float* Wv = (const float*)d_in[6];
  const float* bv = (const float*)d_in[7];
  const float* Wo = (const float*)d_in[8];
  const float* bo = (const float*)d_in[9];
  const float* W1 = (const float*)d_in[10];
  const float* b1 = (const float*)d_in[11];
  const float* W2 = (const float*)d_in[12];
  const float* b2 = (const float*)d_in[13];

  char* ws = (char*)d_ws;
  size_t off = 0;
  auto carve = [&](size_t bytes) -> void* {
    void* p = ws + off;
    off += (bytes + 255) & ~(size_t)255;
    return p;
  };
  __bf16* WqvT = (__bf16*)carve((size_t)1024 * 512 * 2);  // [Wq^T; Wv^T]
  __bf16* WkT  = (__bf16*)carve((size_t)512 * 512 * 2);
  __bf16* WoT  = (__bf16*)carve((size_t)512 * 512 * 2);
  __bf16* W1T  = (__bf16*)carve((size_t)2048 * 512 * 2);
  __bf16* W2T  = (__bf16*)carve((size_t)512 * 2048 * 2);
  int* srcoff = (int*)carve((size_t)NTOK * 4);
  int* outoff = (int*)carve((size_t)NTOK * 4);
  __bf16* Asrc = (__bf16*)carve((size_t)NTOK * 512 * 2);
  __bf16* Aoth = (__bf16*)carve((size_t)NTOK * 512 * 2);
  __bf16* Qb   = (__bf16*)carve((size_t)NTOK * 512 * 2);
  __bf16* Kb   = (__bf16*)carve((size_t)NTOK * 512 * 2);
  __bf16* Vb   = (__bf16*)carve((size_t)NTOK * 512 * 2);
  int nc = 1;
  while (nc < 4 && off + (size_t)(NTOK / nc) * 2048 * 2 > ws_size) nc *= 2;
  int rows = NTOK / nc;
  __bf16* Hb = (__bf16*)carve((size_t)rows * 2048 * 2);
  // aliases (lifetimes: producer of alias runs after last reader of original)
  __bf16* AOb   = Asrc;              // attention out  (Asrc dead after QV-GEMM)
  __bf16* toksb = Aoth;              // tokens bf16    (Aoth dead after K-GEMM)
  float*  dout  = (float*)d_out;

  transpose_all<<<3072, 256, 0, stream>>>(Wq, Wv, Wk, Wo, W1, W2, WqvT, WkT, WoT, W1T, W2T);

  pack_tokens<<<NTOK, 256, 0, stream>>>(x, y, Asrc, Aoth, srcoff, outoff);

  gemm_bt<4><<<NTOK / 128 * 8, 256, 0, stream>>>(Asrc, WqvT, bq, bv, 512, 8, 0, Qb, Vb, nullptr, nullptr, nullptr, nullptr, nullptr, nullptr);
  gemm_bt<0><<<NTOK / 128 * 4, 256, 0, stream>>>(Aoth, WkT, bk, nullptr, 512, 4, 0, Kb, nullptr, nullptr, nullptr, nullptr, nullptr, nullptr, nullptr);

  attn_kernel<<<160 * 8, 512, 0, stream>>>(Qb, Kb, Vb, AOb);

  gemm_bt<1><<<NTOK / 128 * 4, 256, 0, stream>>>(AOb, WoT, bo, nullptr, 512, 4, 0, toksb, nullptr, x, y, srcoff, nullptr, nullptr, nullptr);

  for (int c = 0; c < nc; ++c) {
    int r0 = c * rows;
    gemm_bt<2><<<rows / 128 * 16, 256, 0, stream>>>(toksb + (size_t)r0 * 512, W1T, b1, nullptr, 512, 16, r0, Hb, nullptr, nullptr, nullptr, nullptr, nullptr, nullptr, nullptr);
    gemm_bt<3><<<rows / 128 * 4, 256, 0, stream>>>(Hb, W2T, b2, nullptr, 2048, 4, r0, nullptr, nullptr, nullptr, nullptr, nullptr, outoff, toksb, dout);
  }
}